// Round 1
// baseline (957.041 us; speedup 1.0000x reference)
//
#include <hip/hip_runtime.h>

#define N_NODES 50000
#define N_EDGES 800000
#define NFEAT 128
#define NHID 128
#define NCLASS 10
#define NUM_GRAPHS 512

// ---------------- deg ----------------
__global__ __launch_bounds__(256) void k_init_deg(float* __restrict__ deg) {
  int i = blockIdx.x * 256 + threadIdx.x;
  if (i < N_NODES) deg[i] = 1.0f;  // self loop
}

__global__ __launch_bounds__(256) void k_deg(const int* __restrict__ dst,
                                             float* __restrict__ deg) {
  int e = blockIdx.x * 256 + threadIdx.x;
  if (e < N_EDGES) atomicAdd(&deg[dst[e]], 1.0f);
}

// ---------------- GEMM: Y[r][c] = sum_k X[r][k]*W[k][c], K=C=128 ----------------
// In-place (Y==X) is safe: each row tile is staged into LDS before being written,
// and no block touches another block's rows.
__global__ __launch_bounds__(256) void k_gemm128(const float* __restrict__ X,
                                                 const float* __restrict__ W,
                                                 float* __restrict__ Y) {
  __shared__ float wl[128 * 128];   // 64 KB
  __shared__ float xl[8 * 128];     // 4 KB
  const int tid = threadIdx.x;
  for (int i = tid; i < 128 * 128 / 4; i += 256)
    ((float4*)wl)[i] = ((const float4*)W)[i];
  const int rl = tid >> 5;   // row within tile 0..7
  const int cg = tid & 31;   // col group (4 cols each)
  for (int base = blockIdx.x * 8; base < N_NODES; base += gridDim.x * 8) {
    __syncthreads();  // wl ready (iter 0) / previous iter's xl reads done
    for (int i = tid; i < 8 * 32; i += 256)
      ((float4*)xl)[i] = ((const float4*)(X + base * 128))[i];
    __syncthreads();
    float4 acc = {0.f, 0.f, 0.f, 0.f};
    const float* xr = xl + rl * 128;
#pragma unroll 16
    for (int k = 0; k < 128; ++k) {
      float xv = xr[k];
      float4 wv = ((const float4*)(wl + k * 128))[cg];
      acc.x += xv * wv.x;
      acc.y += xv * wv.y;
      acc.z += xv * wv.z;
      acc.w += xv * wv.w;
    }
    ((float4*)(Y + (base + rl) * 128))[cg] = acc;
  }
}

// ---------------- edge scatter: M[dst] += H[src] ----------------
__global__ __launch_bounds__(256) void k_scatter(const float* __restrict__ H,
                                                 const int* __restrict__ src,
                                                 const int* __restrict__ dst,
                                                 float* __restrict__ M) {
  const int total = N_EDGES * 128;  // 102.4M
  for (int idx = blockIdx.x * 256 + threadIdx.x; idx < total;
       idx += gridDim.x * 256) {
    int e = idx >> 7;
    int d = idx & 127;
    atomicAdd(&M[dst[e] * 128 + d], H[src[e] * 128 + d]);
  }
}

// ---------------- x1 = relu((h1+msg1)/deg); zero A for next scatter ----------------
__global__ __launch_bounds__(256) void k_finish1(float4* __restrict__ A,
                                                 float4* __restrict__ B,
                                                 const float* __restrict__ deg) {
  const int total = N_NODES * 32;
  const float4 z = {0.f, 0.f, 0.f, 0.f};
  for (int i = blockIdx.x * 256 + threadIdx.x; i < total;
       i += gridDim.x * 256) {
    float dg = deg[i >> 5];
    float4 a = A[i], b = B[i];
    float4 v;
    v.x = fmaxf((a.x + b.x) / dg, 0.f);
    v.y = fmaxf((a.y + b.y) / dg, 0.f);
    v.z = fmaxf((a.z + b.z) / dg, 0.f);
    v.w = fmaxf((a.w + b.w) / dg, 0.f);
    B[i] = v;
    A[i] = z;
  }
}

// ---------------- per-graph mean readout (run-length pre-reduced; gid sorted) ----------------
__global__ __launch_bounds__(128) void k_readout(const float* __restrict__ H2,
                                                 const float* __restrict__ M2,
                                                 const float* __restrict__ deg,
                                                 const int* __restrict__ gid,
                                                 float* __restrict__ gsum,
                                                 float* __restrict__ gcnt) {
  const int d = threadIdx.x;  // 0..127
  int r0 = blockIdx.x * 128;
  if (r0 >= N_NODES) return;
  int r1 = min(N_NODES, r0 + 128);
  float acc = 0.f, cacc = 0.f;
  int gcur = gid[r0];
  for (int r = r0; r < r1; ++r) {
    int g = gid[r];  // wave-uniform
    if (g != gcur) {
      atomicAdd(&gsum[gcur * 128 + d], acc);
      if (d == 0) atomicAdd(&gcnt[gcur], cacc);
      acc = 0.f; cacc = 0.f; gcur = g;
    }
    float v = (H2[r * 128 + d] + M2[r * 128 + d]) / deg[r];
    acc += v;
    cacc += 1.f;
  }
  atomicAdd(&gsum[gcur * 128 + d], acc);
  if (d == 0) atomicAdd(&gcnt[gcur], cacc);
}

// ---------------- gmean @ mlp_w + b, log_softmax ----------------
__global__ __launch_bounds__(128) void k_mlp(const float* __restrict__ gsum,
                                             const float* __restrict__ gcnt,
                                             const float* __restrict__ Wm,  // [128][10]
                                             const float* __restrict__ bm,  // [10]
                                             float* __restrict__ out) {
  __shared__ float m[128];
  __shared__ float lg[NCLASS];
  const int g = blockIdx.x;
  const int t = threadIdx.x;
  float cnt = fmaxf(gcnt[g], 1.0f);
  m[t] = gsum[g * 128 + t] / cnt;
  __syncthreads();
  if (t < NCLASS) {
    float s = bm[t];
#pragma unroll
    for (int k = 0; k < 128; ++k) s += m[k] * Wm[k * NCLASS + t];
    lg[t] = s;
  }
  __syncthreads();
  if (t < NCLASS) {
    float mx = lg[0];
#pragma unroll
    for (int i = 1; i < NCLASS; ++i) mx = fmaxf(mx, lg[i]);
    float sum = 0.f;
#pragma unroll
    for (int i = 0; i < NCLASS; ++i) sum += expf(lg[i] - mx);
    out[g * NCLASS + t] = lg[t] - mx - logf(sum);
  }
}

extern "C" void kernel_launch(void* const* d_in, const int* in_sizes, int n_in,
                              void* d_out, int out_size, void* d_ws, size_t ws_size,
                              hipStream_t stream) {
  const float* feat = (const float*)d_in[0];
  const float* W1   = (const float*)d_in[1];
  const float* W2   = (const float*)d_in[2];
  const float* Wm   = (const float*)d_in[3];
  const float* bm   = (const float*)d_in[4];
  const int* esrc   = (const int*)d_in[5];
  const int* edst   = (const int*)d_in[6];
  const int* gid    = (const int*)d_in[7];
  float* out = (float*)d_out;

  // workspace layout (floats): deg | gsum | gcnt | bufA | bufB  (~51.7 MB)
  float* ws   = (float*)d_ws;
  float* deg  = ws;                              // 50048 (padded)
  float* gsum = ws + 50048;                      // 512*128
  float* gcnt = gsum + NUM_GRAPHS * NHID;        // 512
  float* bufA = gcnt + 512;                      // 50000*128
  float* bufB = bufA + N_NODES * NHID;           // 50000*128

  hipMemsetAsync(gsum, 0, (size_t)(NUM_GRAPHS * NHID + 512) * sizeof(float), stream);
  hipMemsetAsync(bufB, 0, (size_t)N_NODES * NHID * sizeof(float), stream);
  k_init_deg<<<(N_NODES + 255) / 256, 256, 0, stream>>>(deg);
  k_deg<<<(N_EDGES + 255) / 256, 256, 0, stream>>>(edst, deg);

  // layer 1: h1 = feat@W1 -> bufA; msg1 -> bufB; x1 = relu((A+B)/deg) -> bufB; A := 0
  k_gemm128<<<512, 256, 0, stream>>>(feat, W1, bufA);
  k_scatter<<<4096, 256, 0, stream>>>(bufA, esrc, edst, bufB);
  k_finish1<<<2048, 256, 0, stream>>>((float4*)bufA, (float4*)bufB, deg);

  // layer 2: h2 = x1@W2 (in-place in bufB); msg2 -> bufA (zeroed by k_finish1)
  k_gemm128<<<512, 256, 0, stream>>>(bufB, W2, bufB);
  k_scatter<<<4096, 256, 0, stream>>>(bufB, esrc, edst, bufA);

  // readout + head
  k_readout<<<(N_NODES + 127) / 128, 128, 0, stream>>>(bufB, bufA, deg, gid, gsum, gcnt);
  k_mlp<<<NUM_GRAPHS, 128, 0, stream>>>(gsum, gcnt, Wm, bm, out);
}

// Round 2
// 509.599 us; speedup vs baseline: 1.8780x; 1.8780x over previous
//
#include <hip/hip_runtime.h>

#define N_NODES 50000
#define N_EDGES 800000
#define NFEAT 128
#define NHID 128
#define NCLASS 10
#define NUM_GRAPHS 512

// ---------------- CSR build ----------------
__global__ __launch_bounds__(256) void k_count(const int* __restrict__ dst,
                                               int* __restrict__ cnt) {
  int e = blockIdx.x * 256 + threadIdx.x;
  if (e < N_EDGES) atomicAdd(&cnt[dst[e]], 1);
}

// single-block exclusive scan of cnt[0..N_NODES) -> rs; rs[N_NODES]=N_EDGES
__global__ __launch_bounds__(1024) void k_scan(const int* __restrict__ cnt,
                                               int* __restrict__ rs) {
  __shared__ int sdata[1024];
  __shared__ int soff;
  const int tid = threadIdx.x;
  if (tid == 0) soff = 0;
  __syncthreads();
  for (int base = 0; base < N_NODES; base += 1024) {
    int i = base + tid;
    int v = (i < N_NODES) ? cnt[i] : 0;
    sdata[tid] = v;
    __syncthreads();
    for (int s = 1; s < 1024; s <<= 1) {
      int t = (tid >= s) ? sdata[tid - s] : 0;
      __syncthreads();
      sdata[tid] += t;
      __syncthreads();
    }
    if (i < N_NODES) rs[i] = soff + sdata[tid] - v;  // exclusive
    __syncthreads();
    if (tid == 1023) soff += sdata[1023];
    __syncthreads();
  }
  if (tid == 0) rs[N_NODES] = soff;
}

__global__ __launch_bounds__(256) void k_bucket(const int* __restrict__ src,
                                                const int* __restrict__ dst,
                                                const int* __restrict__ rs,
                                                int* __restrict__ cursor,
                                                int* __restrict__ csr) {
  int e = blockIdx.x * 256 + threadIdx.x;
  if (e < N_EDGES) {
    int d = dst[e];
    int p = atomicAdd(&cursor[d], 1);
    csr[rs[d] + p] = src[e];
  }
}

// ---------------- GEMM: Y[r][c] = sum_k X[r][k]*W[k][c], K=C=128 ----------------
// In-place (Y==X) safe: row tile staged to LDS before being overwritten.
__global__ __launch_bounds__(256) void k_gemm128(const float* __restrict__ X,
                                                 const float* __restrict__ W,
                                                 float* __restrict__ Y) {
  __shared__ float wl[128 * 128];   // 64 KB
  __shared__ float xl[8 * 128];     // 4 KB
  const int tid = threadIdx.x;
  for (int i = tid; i < 128 * 128 / 4; i += 256)
    ((float4*)wl)[i] = ((const float4*)W)[i];
  const int rl = tid >> 5;   // row within tile 0..7
  const int cg = tid & 31;   // col group (4 cols)
  for (int base = blockIdx.x * 8; base < N_NODES; base += gridDim.x * 8) {
    __syncthreads();
    for (int i = tid; i < 8 * 32; i += 256)
      ((float4*)xl)[i] = ((const float4*)(X + base * 128))[i];
    __syncthreads();
    float4 acc = {0.f, 0.f, 0.f, 0.f};
    const float* xr = xl + rl * 128;
#pragma unroll 16
    for (int k = 0; k < 128; ++k) {
      float xv = xr[k];
      float4 wv = ((const float4*)(wl + k * 128))[cg];
      acc.x += xv * wv.x;
      acc.y += xv * wv.y;
      acc.z += xv * wv.z;
      acc.w += xv * wv.w;
    }
    ((float4*)(Y + (base + rl) * 128))[cg] = acc;
  }
}

// ---------------- gather-aggregate: Out[n] = act((H[n] + sum_{s in N(n)} H[s]) / deg) ----
// one wave (64 lanes) per node; lane handles float2 (2 cols). Row read = 512B coalesced.
template <bool RELU>
__global__ __launch_bounds__(256) void k_agg(const float* __restrict__ H,
                                             const int* __restrict__ csr,
                                             const int* __restrict__ rs,
                                             float* __restrict__ Out) {
  const int node = blockIdx.x * 4 + (threadIdx.x >> 6);
  if (node >= N_NODES) return;
  const int lane = threadIdx.x & 63;
  const int beg = rs[node], end = rs[node + 1];
  const float2* __restrict__ H2 = (const float2*)H;
  float2 acc = {0.f, 0.f};
  int e = beg;
  for (; e + 4 <= end; e += 4) {
    int s0 = csr[e], s1 = csr[e + 1], s2 = csr[e + 2], s3 = csr[e + 3];
    float2 v0 = H2[(size_t)s0 * 64 + lane];
    float2 v1 = H2[(size_t)s1 * 64 + lane];
    float2 v2 = H2[(size_t)s2 * 64 + lane];
    float2 v3 = H2[(size_t)s3 * 64 + lane];
    acc.x += (v0.x + v1.x) + (v2.x + v3.x);
    acc.y += (v0.y + v1.y) + (v2.y + v3.y);
  }
  for (; e < end; ++e) {
    int s = csr[e];
    float2 v = H2[(size_t)s * 64 + lane];
    acc.x += v.x;
    acc.y += v.y;
  }
  float2 h = H2[(size_t)node * 64 + lane];
  float inv = 1.0f / (float)(end - beg + 1);
  float2 r;
  r.x = (h.x + acc.x) * inv;
  r.y = (h.y + acc.y) * inv;
  if (RELU) {
    r.x = fmaxf(r.x, 0.f);
    r.y = fmaxf(r.y, 0.f);
  }
  ((float2*)Out)[(size_t)node * 64 + lane] = r;
}

// ---------------- per-graph mean readout (gid sorted -> run-length reduce) ----------------
__global__ __launch_bounds__(128) void k_readout(const float* __restrict__ X2,
                                                 const int* __restrict__ gid,
                                                 float* __restrict__ gsum,
                                                 float* __restrict__ gcnt) {
  const int d = threadIdx.x;  // 0..127
  int r0 = blockIdx.x * 128;
  if (r0 >= N_NODES) return;
  int r1 = min(N_NODES, r0 + 128);
  float acc = 0.f, cacc = 0.f;
  int gcur = gid[r0];
  for (int r = r0; r < r1; ++r) {
    int g = gid[r];  // wave-uniform
    if (g != gcur) {
      atomicAdd(&gsum[gcur * 128 + d], acc);
      if (d == 0) atomicAdd(&gcnt[gcur], cacc);
      acc = 0.f; cacc = 0.f; gcur = g;
    }
    acc += X2[(size_t)r * 128 + d];
    cacc += 1.f;
  }
  atomicAdd(&gsum[gcur * 128 + d], acc);
  if (d == 0) atomicAdd(&gcnt[gcur], cacc);
}

// ---------------- gmean @ mlp_w + b, log_softmax ----------------
__global__ __launch_bounds__(128) void k_mlp(const float* __restrict__ gsum,
                                             const float* __restrict__ gcnt,
                                             const float* __restrict__ Wm,  // [128][10]
                                             const float* __restrict__ bm,  // [10]
                                             float* __restrict__ out) {
  __shared__ float m[128];
  __shared__ float lg[NCLASS];
  const int g = blockIdx.x;
  const int t = threadIdx.x;
  float cnt = fmaxf(gcnt[g], 1.0f);
  m[t] = gsum[g * 128 + t] / cnt;
  __syncthreads();
  if (t < NCLASS) {
    float s = bm[t];
#pragma unroll
    for (int k = 0; k < 128; ++k) s += m[k] * Wm[k * NCLASS + t];
    lg[t] = s;
  }
  __syncthreads();
  if (t < NCLASS) {
    float mx = lg[0];
#pragma unroll
    for (int i = 1; i < NCLASS; ++i) mx = fmaxf(mx, lg[i]);
    float sum = 0.f;
#pragma unroll
    for (int i = 0; i < NCLASS; ++i) sum += expf(lg[i] - mx);
    out[g * NCLASS + t] = lg[t] - mx - logf(sum);
  }
}

extern "C" void kernel_launch(void* const* d_in, const int* in_sizes, int n_in,
                              void* d_out, int out_size, void* d_ws, size_t ws_size,
                              hipStream_t stream) {
  const float* feat = (const float*)d_in[0];
  const float* W1   = (const float*)d_in[1];
  const float* W2   = (const float*)d_in[2];
  const float* Wm   = (const float*)d_in[3];
  const float* bm   = (const float*)d_in[4];
  const int* esrc   = (const int*)d_in[5];
  const int* edst   = (const int*)d_in[6];
  const int* gid    = (const int*)d_in[7];
  float* out = (float*)d_out;

  // workspace layout:
  // ints:   cnt[50048] | cursor[50048] | rs[50056] | csr[800000]
  // floats: gsum[512*128] | gcnt[512] | bufA[50000*128] | bufB[50000*128]
  int* cnt    = (int*)d_ws;
  int* cursor = cnt + 50048;
  int* rs     = cursor + 50048;
  int* csr    = rs + 50056;
  float* gsum = (float*)(csr + 800000);
  float* gcnt = gsum + NUM_GRAPHS * NHID;
  float* bufA = gcnt + 512;
  float* bufB = bufA + (size_t)N_NODES * NHID;

  // zero: cnt+cursor (adjacent), gsum+gcnt (adjacent)
  hipMemsetAsync(cnt, 0, (size_t)(50048 + 50048) * sizeof(int), stream);
  hipMemsetAsync(gsum, 0, (size_t)(NUM_GRAPHS * NHID + 512) * sizeof(float), stream);

  // CSR build (graph is reused by both layers)
  k_count<<<(N_EDGES + 255) / 256, 256, 0, stream>>>(edst, cnt);
  k_scan<<<1, 1024, 0, stream>>>(cnt, rs);
  k_bucket<<<(N_EDGES + 255) / 256, 256, 0, stream>>>(esrc, edst, rs, cursor, csr);

  // layer 1: h1 = feat@W1 -> bufA; x1 = relu((h1+gather)/deg) -> bufB
  k_gemm128<<<512, 256, 0, stream>>>(feat, W1, bufA);
  k_agg<true><<<(N_NODES + 3) / 4, 256, 0, stream>>>(bufA, csr, rs, bufB);

  // layer 2: h2 = x1@W2 in-place in bufB; x2 = (h2+gather)/deg -> bufA
  k_gemm128<<<512, 256, 0, stream>>>(bufB, W2, bufB);
  k_agg<false><<<(N_NODES + 3) / 4, 256, 0, stream>>>(bufB, csr, rs, bufA);

  // readout + head
  k_readout<<<(N_NODES + 127) / 128, 128, 0, stream>>>(bufA, gid, gsum, gcnt);
  k_mlp<<<NUM_GRAPHS, 128, 0, stream>>>(gsum, gcnt, Wm, bm, out);
}

// Round 3
// 438.945 us; speedup vs baseline: 2.1803x; 1.1610x over previous
//
#include <hip/hip_runtime.h>

#define N_NODES 50000
#define N_EDGES 800000
#define NFEAT 128
#define NHID 128
#define NCLASS 10
#define NUM_GRAPHS 512
#define SCAN_NBLK 49  // ceil(50000/1024)

// ---------------- CSR build ----------------
__global__ __launch_bounds__(256) void k_count(const int* __restrict__ dst,
                                               int* __restrict__ cnt) {
  int e = blockIdx.x * 256 + threadIdx.x;
  if (e < N_EDGES) atomicAdd(&cnt[dst[e]], 1);
}

// two-level scan: (1) per-block local exclusive scan + block sums
__global__ __launch_bounds__(1024) void k_scan1(const int* __restrict__ cnt,
                                                int* __restrict__ rs,
                                                int* __restrict__ bsum) {
  __shared__ int sdata[1024];
  const int tid = threadIdx.x;
  const int i = blockIdx.x * 1024 + tid;
  int v = (i < N_NODES) ? cnt[i] : 0;
  sdata[tid] = v;
  __syncthreads();
  for (int s = 1; s < 1024; s <<= 1) {
    int t = (tid >= s) ? sdata[tid - s] : 0;
    __syncthreads();
    sdata[tid] += t;
    __syncthreads();
  }
  if (i < N_NODES) rs[i] = sdata[tid] - v;  // local exclusive
  if (tid == 1023) bsum[blockIdx.x] = sdata[1023];
}

// (2) scan the block sums (SCAN_NBLK <= 64) in one wave; set rs[N]
__global__ __launch_bounds__(64) void k_scan2(int* __restrict__ bsum,
                                              int* __restrict__ rs) {
  __shared__ int s[64];
  const int t = threadIdx.x;
  int v = (t < SCAN_NBLK) ? bsum[t] : 0;
  s[t] = v;
  __syncthreads();
  for (int d = 1; d < 64; d <<= 1) {
    int u = (t >= d) ? s[t - d] : 0;
    __syncthreads();
    s[t] += u;
    __syncthreads();
  }
  if (t < SCAN_NBLK) bsum[t] = s[t] - v;  // exclusive block offsets
  if (t == 0) rs[N_NODES] = N_EDGES;
}

// (3) add block offsets
__global__ __launch_bounds__(1024) void k_scan3(int* __restrict__ rs,
                                                const int* __restrict__ bsum) {
  const int i = blockIdx.x * 1024 + threadIdx.x;
  if (i < N_NODES) rs[i] += bsum[blockIdx.x];
}

__global__ __launch_bounds__(256) void k_bucket(const int* __restrict__ src,
                                                const int* __restrict__ dst,
                                                const int* __restrict__ rs,
                                                int* __restrict__ cursor,
                                                int* __restrict__ csr) {
  int e = blockIdx.x * 256 + threadIdx.x;
  if (e < N_EDGES) {
    int d = dst[e];
    int p = atomicAdd(&cursor[d], 1);
    csr[rs[d] + p] = src[e];
  }
}

// ---------------- GEMM: Y[r][c] = sum_k X[r][k]*W[k][c], K=C=128 ----------------
// In-place (Y==X) safe: row tile staged to LDS before being overwritten.
__global__ __launch_bounds__(256) void k_gemm128(const float* __restrict__ X,
                                                 const float* __restrict__ W,
                                                 float* __restrict__ Y) {
  __shared__ float wl[128 * 128];   // 64 KB
  __shared__ float xl[8 * 128];     // 4 KB
  const int tid = threadIdx.x;
  for (int i = tid; i < 128 * 128 / 4; i += 256)
    ((float4*)wl)[i] = ((const float4*)W)[i];
  const int rl = tid >> 5;   // row within tile 0..7
  const int cg = tid & 31;   // col group (4 cols)
  for (int base = blockIdx.x * 8; base < N_NODES; base += gridDim.x * 8) {
    __syncthreads();
    for (int i = tid; i < 8 * 32; i += 256)
      ((float4*)xl)[i] = ((const float4*)(X + base * 128))[i];
    __syncthreads();
    float4 acc = {0.f, 0.f, 0.f, 0.f};
    const float* xr = xl + rl * 128;
#pragma unroll 16
    for (int k = 0; k < 128; ++k) {
      float xv = xr[k];
      float4 wv = ((const float4*)(wl + k * 128))[cg];
      acc.x += xv * wv.x;
      acc.y += xv * wv.y;
      acc.z += xv * wv.z;
      acc.w += xv * wv.w;
    }
    ((float4*)(Y + (base + rl) * 128))[cg] = acc;
  }
}

// ---------------- gather-aggregate: Out[n] = act((H[n] + sum_{s in N(n)} H[s]) / deg) ----
// one wave (64 lanes) per node; lane handles float2 (2 cols). Row read = 512B coalesced.
template <bool RELU>
__global__ __launch_bounds__(256) void k_agg(const float* __restrict__ H,
                                             const int* __restrict__ csr,
                                             const int* __restrict__ rs,
                                             float* __restrict__ Out) {
  const int node = blockIdx.x * 4 + (threadIdx.x >> 6);
  if (node >= N_NODES) return;
  const int lane = threadIdx.x & 63;
  const int beg = rs[node], end = rs[node + 1];
  const float2* __restrict__ H2 = (const float2*)H;
  float2 acc = {0.f, 0.f};
  int e = beg;
  for (; e + 4 <= end; e += 4) {
    int s0 = csr[e], s1 = csr[e + 1], s2 = csr[e + 2], s3 = csr[e + 3];
    float2 v0 = H2[(size_t)s0 * 64 + lane];
    float2 v1 = H2[(size_t)s1 * 64 + lane];
    float2 v2 = H2[(size_t)s2 * 64 + lane];
    float2 v3 = H2[(size_t)s3 * 64 + lane];
    acc.x += (v0.x + v1.x) + (v2.x + v3.x);
    acc.y += (v0.y + v1.y) + (v2.y + v3.y);
  }
  for (; e < end; ++e) {
    int s = csr[e];
    float2 v = H2[(size_t)s * 64 + lane];
    acc.x += v.x;
    acc.y += v.y;
  }
  float2 h = H2[(size_t)node * 64 + lane];
  float inv = 1.0f / (float)(end - beg + 1);
  float2 r;
  r.x = (h.x + acc.x) * inv;
  r.y = (h.y + acc.y) * inv;
  if (RELU) {
    r.x = fmaxf(r.x, 0.f);
    r.y = fmaxf(r.y, 0.f);
  }
  ((float2*)Out)[(size_t)node * 64 + lane] = r;
}

// ---------------- per-graph mean readout (gid sorted -> run-length reduce) ----------------
__global__ __launch_bounds__(128) void k_readout(const float* __restrict__ X2,
                                                 const int* __restrict__ gid,
                                                 float* __restrict__ gsum,
                                                 float* __restrict__ gcnt) {
  const int d = threadIdx.x;  // 0..127
  int r0 = blockIdx.x * 128;
  if (r0 >= N_NODES) return;
  int r1 = min(N_NODES, r0 + 128);
  float acc = 0.f, cacc = 0.f;
  int gcur = gid[r0];
  for (int r = r0; r < r1; ++r) {
    int g = gid[r];  // wave-uniform
    if (g != gcur) {
      atomicAdd(&gsum[gcur * 128 + d], acc);
      if (d == 0) atomicAdd(&gcnt[gcur], cacc);
      acc = 0.f; cacc = 0.f; gcur = g;
    }
    acc += X2[(size_t)r * 128 + d];
    cacc += 1.f;
  }
  atomicAdd(&gsum[gcur * 128 + d], acc);
  if (d == 0) atomicAdd(&gcnt[gcur], cacc);
}

// ---------------- gmean @ mlp_w + b, log_softmax ----------------
__global__ __launch_bounds__(128) void k_mlp(const float* __restrict__ gsum,
                                             const float* __restrict__ gcnt,
                                             const float* __restrict__ Wm,  // [128][10]
                                             const float* __restrict__ bm,  // [10]
                                             float* __restrict__ out) {
  __shared__ float m[128];
  __shared__ float lg[NCLASS];
  const int g = blockIdx.x;
  const int t = threadIdx.x;
  float cnt = fmaxf(gcnt[g], 1.0f);
  m[t] = gsum[g * 128 + t] / cnt;
  __syncthreads();
  if (t < NCLASS) {
    float s = bm[t];
#pragma unroll
    for (int k = 0; k < 128; ++k) s += m[k] * Wm[k * NCLASS + t];
    lg[t] = s;
  }
  __syncthreads();
  if (t < NCLASS) {
    float mx = lg[0];
#pragma unroll
    for (int i = 1; i < NCLASS; ++i) mx = fmaxf(mx, lg[i]);
    float sum = 0.f;
#pragma unroll
    for (int i = 0; i < NCLASS; ++i) sum += expf(lg[i] - mx);
    out[g * NCLASS + t] = lg[t] - mx - logf(sum);
  }
}

extern "C" void kernel_launch(void* const* d_in, const int* in_sizes, int n_in,
                              void* d_out, int out_size, void* d_ws, size_t ws_size,
                              hipStream_t stream) {
  const float* feat = (const float*)d_in[0];
  const float* W1   = (const float*)d_in[1];
  const float* W2   = (const float*)d_in[2];
  const float* Wm   = (const float*)d_in[3];
  const float* bm   = (const float*)d_in[4];
  const int* esrc   = (const int*)d_in[5];
  const int* edst   = (const int*)d_in[6];
  const int* gid    = (const int*)d_in[7];
  float* out = (float*)d_out;

  // workspace layout:
  // ints:   cnt[50048] | cursor[50048] | rs[50056] | bsum[64] | csr[800000]
  // floats: gsum[512*128] | gcnt[512] | bufA[50000*128] | bufB[50000*128]
  int* cnt    = (int*)d_ws;
  int* cursor = cnt + 50048;
  int* rs     = cursor + 50048;
  int* bsum   = rs + 50056;
  int* csr    = bsum + 64;
  float* gsum = (float*)(csr + 800000);
  float* gcnt = gsum + NUM_GRAPHS * NHID;
  float* bufA = gcnt + 512;
  float* bufB = bufA + (size_t)N_NODES * NHID;

  hipMemsetAsync(cnt, 0, (size_t)(50048 + 50048) * sizeof(int), stream);
  hipMemsetAsync(gsum, 0, (size_t)(NUM_GRAPHS * NHID + 512) * sizeof(float), stream);

  // CSR build (graph reused by both layers)
  k_count<<<(N_EDGES + 255) / 256, 256, 0, stream>>>(edst, cnt);
  k_scan1<<<SCAN_NBLK, 1024, 0, stream>>>(cnt, rs, bsum);
  k_scan2<<<1, 64, 0, stream>>>(bsum, rs);
  k_scan3<<<SCAN_NBLK, 1024, 0, stream>>>(rs, bsum);
  k_bucket<<<(N_EDGES + 255) / 256, 256, 0, stream>>>(esrc, edst, rs, cursor, csr);

  // layer 1: h1 = feat@W1 -> bufA; x1 = relu((h1+gather)/deg) -> bufB
  k_gemm128<<<512, 256, 0, stream>>>(feat, W1, bufA);
  k_agg<true><<<(N_NODES + 3) / 4, 256, 0, stream>>>(bufA, csr, rs, bufB);

  // layer 2: h2 = x1@W2 in-place in bufB; x2 = (h2+gather)/deg -> bufA
  k_gemm128<<<512, 256, 0, stream>>>(bufB, W2, bufB);
  k_agg<false><<<(N_NODES + 3) / 4, 256, 0, stream>>>(bufB, csr, rs, bufA);

  // readout + head
  k_readout<<<(N_NODES + 127) / 128, 128, 0, stream>>>(bufA, gid, gsum, gcnt);
  k_mlp<<<NUM_GRAPHS, 128, 0, stream>>>(gsum, gcnt, Wm, bm, out);
}

// Round 4
// 327.871 us; speedup vs baseline: 2.9190x; 1.3388x over previous
//
#include <hip/hip_runtime.h>

#define N_NODES 50000
#define N_EDGES 800000
#define NFEAT 128
#define NHID 128
#define NCLASS 10
#define NUM_GRAPHS 512
#define SCAN_NBLK 49       // ceil(50000/1024)
#define GEMM_BLOCKS 782    // ceil(50000/64)

typedef __attribute__((ext_vector_type(8))) short bf16x8;
typedef __attribute__((ext_vector_type(4))) float f32x4;

__device__ inline ushort f2bf(float f) {
  union { float f; uint u; } c; c.f = f;
  return (ushort)((c.u + 0x7fffu + ((c.u >> 16) & 1u)) >> 16);
}
__device__ inline float bf2f_lo(uint u) { union { uint u; float f; } c; c.u = u << 16; return c.f; }
__device__ inline float bf2f_hi(uint u) { union { uint u; float f; } c; c.u = u & 0xffff0000u; return c.f; }
__device__ inline float bf2f_s(ushort h) { union { uint u; float f; } c; c.u = ((uint)h) << 16; return c.f; }

// ---------------- CSR build ----------------
__global__ __launch_bounds__(256) void k_count(const int* __restrict__ dst,
                                               int* __restrict__ cnt) {
  int e = blockIdx.x * 256 + threadIdx.x;
  if (e < N_EDGES) atomicAdd(&cnt[dst[e]], 1);
}

__global__ __launch_bounds__(1024) void k_scan1(const int* __restrict__ cnt,
                                                int* __restrict__ rs,
                                                int* __restrict__ bsum) {
  __shared__ int sdata[1024];
  const int tid = threadIdx.x;
  const int i = blockIdx.x * 1024 + tid;
  int v = (i < N_NODES) ? cnt[i] : 0;
  sdata[tid] = v;
  __syncthreads();
  for (int s = 1; s < 1024; s <<= 1) {
    int t = (tid >= s) ? sdata[tid - s] : 0;
    __syncthreads();
    sdata[tid] += t;
    __syncthreads();
  }
  if (i < N_NODES) rs[i] = sdata[tid] - v;  // local exclusive
  if (tid == 1023) bsum[blockIdx.x] = sdata[1023];
}

__global__ __launch_bounds__(64) void k_scan2(int* __restrict__ bsum,
                                              int* __restrict__ rs) {
  __shared__ int s[64];
  const int t = threadIdx.x;
  int v = (t < SCAN_NBLK) ? bsum[t] : 0;
  s[t] = v;
  __syncthreads();
  for (int d = 1; d < 64; d <<= 1) {
    int u = (t >= d) ? s[t - d] : 0;
    __syncthreads();
    s[t] += u;
    __syncthreads();
  }
  if (t < SCAN_NBLK) bsum[t] = s[t] - v;
  if (t == 0) rs[N_NODES] = N_EDGES;
}

__global__ __launch_bounds__(1024) void k_scan3(int* __restrict__ rs,
                                                const int* __restrict__ bsum) {
  const int i = blockIdx.x * 1024 + threadIdx.x;
  if (i < N_NODES) rs[i] += bsum[blockIdx.x];
}

__global__ __launch_bounds__(256) void k_bucket(const int* __restrict__ src,
                                                const int* __restrict__ dst,
                                                const int* __restrict__ rs,
                                                int* __restrict__ cursor,
                                                int* __restrict__ csr) {
  int e = blockIdx.x * 256 + threadIdx.x;
  if (e < N_EDGES) {
    int d = dst[e];
    int p = atomicAdd(&cursor[d], 1);
    csr[rs[d] + p] = src[e];
  }
}

// ---------------- W pre-pack into MFMA B-fragment order (once per W) ----------------
// dst[((nt*4+ks)*64+lane)*8+e] = bf16( W[ ks*32 + (lane>>4)*8 + e ][ nt*16 + (lane&15) ] )
__global__ __launch_bounds__(256) void k_wpack(const float* __restrict__ W,
                                               ushort* __restrict__ out) {
  int idx = blockIdx.x * 256 + threadIdx.x;  // 0..16383
  int frag = idx >> 9;
  int lane = (idx >> 3) & 63;
  int e = idx & 7;
  int nt = frag >> 2, ks = frag & 3;
  int c = nt * 16 + (lane & 15);
  int k = ks * 32 + (lane >> 4) * 8 + e;
  out[idx] = f2bf(W[k * 128 + c]);
}

// ---------------- MFMA GEMM: Y[bf16] = X @ W, X 50000x128, W 128x128 ----------------
// 256 thr = 4 waves; block tile 64 rows x 128 cols; K=128 in 4 steps of 32.
template <bool XFP32>
__global__ __launch_bounds__(256) void k_gemm_mfma(const void* __restrict__ Xv,
                                                   const ushort* __restrict__ Wp,
                                                   ushort* __restrict__ Y) {
  __shared__ ushort xs[4 * 4 * 64 * 8];   // 16 KB, [wt][ks][lane][8]
  __shared__ ushort wsh[32 * 64 * 8];     // 32 KB, packed W fragments
  const int tid = threadIdx.x;
  const int base = blockIdx.x * 64;
  const int rem = N_NODES - base;

  for (int i = tid; i < 2048; i += 256)
    ((uint4*)wsh)[i] = ((const uint4*)Wp)[i];

  // stage X tile as packed A-fragments: row=lane&15, k=8*(lane>>4)+e
  for (int g = tid; g < 1024; g += 256) {
    int row = g >> 4;
    int k0 = (g & 15) << 3;
    int wt = row >> 4, ks = k0 >> 5;
    int lane = (row & 15) + (((k0 >> 3) & 3) << 4);
    uint4 v;
    if (row < rem) {
      if (XFP32) {
        const float* s = (const float*)Xv + (size_t)(base + row) * 128 + k0;
        float4 p0 = ((const float4*)s)[0];
        float4 p1 = ((const float4*)s)[1];
        v.x = (uint)f2bf(p0.x) | ((uint)f2bf(p0.y) << 16);
        v.y = (uint)f2bf(p0.z) | ((uint)f2bf(p0.w) << 16);
        v.z = (uint)f2bf(p1.x) | ((uint)f2bf(p1.y) << 16);
        v.w = (uint)f2bf(p1.z) | ((uint)f2bf(p1.w) << 16);
      } else {
        v = *(const uint4*)((const ushort*)Xv + (size_t)(base + row) * 128 + k0);
      }
    } else {
      v.x = 0; v.y = 0; v.z = 0; v.w = 0;
    }
    *(uint4*)&xs[((((wt << 2) + ks) << 6) + lane) << 3] = v;
  }
  __syncthreads();

  const int wave = tid >> 6, lane = tid & 63;
  f32x4 acc[8];
#pragma unroll
  for (int i = 0; i < 8; ++i) acc[i] = f32x4{0.f, 0.f, 0.f, 0.f};
  bf16x8 a[4];
#pragma unroll
  for (int ks = 0; ks < 4; ++ks)
    a[ks] = *(const bf16x8*)&xs[((((wave << 2) + ks) << 6) + lane) << 3];
#pragma unroll
  for (int ks = 0; ks < 4; ++ks) {
#pragma unroll
    for (int nt = 0; nt < 8; ++nt) {
      bf16x8 b = *(const bf16x8*)&wsh[((((nt << 2) + ks) << 6) + lane) << 3];
      acc[nt] = __builtin_amdgcn_mfma_f32_16x16x32_bf16(a[ks], b, acc[nt], 0, 0, 0);
    }
  }
  // C/D: col = lane&15, row = (lane>>4)*4 + reg
  const int r0 = base + wave * 16 + ((lane >> 4) << 2);
  const int c0 = lane & 15;
#pragma unroll
  for (int nt = 0; nt < 8; ++nt)
#pragma unroll
    for (int r = 0; r < 4; ++r) {
      int row = r0 + r;
      if (row < N_NODES)
        Y[(size_t)row * 128 + (nt << 4) + c0] = f2bf(acc[nt][r]);
    }
}

// ---------------- gather-aggregate (bf16 rows, fp32 accumulate) ----------------
template <bool RELU>
__global__ __launch_bounds__(256) void k_agg(const ushort* __restrict__ H,
                                             const int* __restrict__ csr,
                                             const int* __restrict__ rs,
                                             ushort* __restrict__ Out) {
  const int node = blockIdx.x * 4 + (threadIdx.x >> 6);
  if (node >= N_NODES) return;
  const int lane = threadIdx.x & 63;
  const int beg = rs[node], end = rs[node + 1];
  const uint* __restrict__ H2 = (const uint*)H;  // 2 bf16 per uint
  float ax = 0.f, ay = 0.f;
  int e = beg;
  for (; e + 4 <= end; e += 4) {
    int s0 = csr[e], s1 = csr[e + 1], s2 = csr[e + 2], s3 = csr[e + 3];
    uint u0 = H2[(size_t)s0 * 64 + lane];
    uint u1 = H2[(size_t)s1 * 64 + lane];
    uint u2 = H2[(size_t)s2 * 64 + lane];
    uint u3 = H2[(size_t)s3 * 64 + lane];
    ax += (bf2f_lo(u0) + bf2f_lo(u1)) + (bf2f_lo(u2) + bf2f_lo(u3));
    ay += (bf2f_hi(u0) + bf2f_hi(u1)) + (bf2f_hi(u2) + bf2f_hi(u3));
  }
  for (; e < end; ++e) {
    uint u = H2[(size_t)csr[e] * 64 + lane];
    ax += bf2f_lo(u);
    ay += bf2f_hi(u);
  }
  uint uh = H2[(size_t)node * 64 + lane];
  float inv = 1.0f / (float)(end - beg + 1);
  float rx = (bf2f_lo(uh) + ax) * inv;
  float ry = (bf2f_hi(uh) + ay) * inv;
  if (RELU) {
    rx = fmaxf(rx, 0.f);
    ry = fmaxf(ry, 0.f);
  }
  ((uint*)Out)[(size_t)node * 64 + lane] = (uint)f2bf(rx) | ((uint)f2bf(ry) << 16);
}

// ---------------- per-graph mean readout (gid sorted -> run-length reduce) ----------------
__global__ __launch_bounds__(128) void k_readout(const ushort* __restrict__ X2,
                                                 const int* __restrict__ gid,
                                                 float* __restrict__ gsum,
                                                 float* __restrict__ gcnt) {
  const int d = threadIdx.x;  // 0..127
  int r0 = blockIdx.x * 128;
  if (r0 >= N_NODES) return;
  int r1 = min(N_NODES, r0 + 128);
  float acc = 0.f, cacc = 0.f;
  int gcur = gid[r0];
  for (int r = r0; r < r1; ++r) {
    int g = gid[r];  // wave-uniform
    if (g != gcur) {
      atomicAdd(&gsum[gcur * 128 + d], acc);
      if (d == 0) atomicAdd(&gcnt[gcur], cacc);
      acc = 0.f; cacc = 0.f; gcur = g;
    }
    acc += bf2f_s(X2[(size_t)r * 128 + d]);
    cacc += 1.f;
  }
  atomicAdd(&gsum[gcur * 128 + d], acc);
  if (d == 0) atomicAdd(&gcnt[gcur], cacc);
}

// ---------------- gmean @ mlp_w + b, log_softmax ----------------
__global__ __launch_bounds__(128) void k_mlp(const float* __restrict__ gsum,
                                             const float* __restrict__ gcnt,
                                             const float* __restrict__ Wm,
                                             const float* __restrict__ bm,
                                             float* __restrict__ out) {
  __shared__ float m[128];
  __shared__ float lg[NCLASS];
  const int g = blockIdx.x;
  const int t = threadIdx.x;
  float cnt = fmaxf(gcnt[g], 1.0f);
  m[t] = gsum[g * 128 + t] / cnt;
  __syncthreads();
  if (t < NCLASS) {
    float s = bm[t];
#pragma unroll
    for (int k = 0; k < 128; ++k) s += m[k] * Wm[k * NCLASS + t];
    lg[t] = s;
  }
  __syncthreads();
  if (t < NCLASS) {
    float mx = lg[0];
#pragma unroll
    for (int i = 1; i < NCLASS; ++i) mx = fmaxf(mx, lg[i]);
    float sum = 0.f;
#pragma unroll
    for (int i = 0; i < NCLASS; ++i) sum += expf(lg[i] - mx);
    out[g * NCLASS + t] = lg[t] - mx - logf(sum);
  }
}

extern "C" void kernel_launch(void* const* d_in, const int* in_sizes, int n_in,
                              void* d_out, int out_size, void* d_ws, size_t ws_size,
                              hipStream_t stream) {
  const float* feat = (const float*)d_in[0];
  const float* W1   = (const float*)d_in[1];
  const float* W2   = (const float*)d_in[2];
  const float* Wm   = (const float*)d_in[3];
  const float* bm   = (const float*)d_in[4];
  const int* esrc   = (const int*)d_in[5];
  const int* edst   = (const int*)d_in[6];
  const int* gid    = (const int*)d_in[7];
  float* out = (float*)d_out;

  // workspace layout:
  // ints:   cnt[50048] | cursor[50048] | rs[50056] | bsum[64] | csr[800000]
  // ushort: wp1[16384] | wp2[16384] | bufA[50000*128] | bufB[50000*128]
  // float:  gsum[512*128] | gcnt[512]
  int* cnt    = (int*)d_ws;
  int* cursor = cnt + 50048;
  int* rs     = cursor + 50048;
  int* bsum   = rs + 50056;
  int* csr    = bsum + 64;
  ushort* wp1 = (ushort*)(csr + 800000);
  ushort* wp2 = wp1 + 16384;
  ushort* bufA = wp2 + 16384;
  ushort* bufB = bufA + (size_t)N_NODES * NHID;
  float* gsum = (float*)(bufB + (size_t)N_NODES * NHID);
  float* gcnt = gsum + NUM_GRAPHS * NHID;

  hipMemsetAsync(cnt, 0, (size_t)(50048 + 50048) * sizeof(int), stream);
  hipMemsetAsync(gsum, 0, (size_t)(NUM_GRAPHS * NHID + 512) * sizeof(float), stream);

  // CSR build + W pre-pack
  k_count<<<(N_EDGES + 255) / 256, 256, 0, stream>>>(edst, cnt);
  k_wpack<<<64, 256, 0, stream>>>(W1, wp1);
  k_wpack<<<64, 256, 0, stream>>>(W2, wp2);
  k_scan1<<<SCAN_NBLK, 1024, 0, stream>>>(cnt, rs, bsum);
  k_scan2<<<1, 64, 0, stream>>>(bsum, rs);
  k_scan3<<<SCAN_NBLK, 1024, 0, stream>>>(rs, bsum);
  k_bucket<<<(N_EDGES + 255) / 256, 256, 0, stream>>>(esrc, edst, rs, cursor, csr);

  // layer 1: h1 = feat@W1 -> bufA (bf16); x1 = relu((h1+gather)/deg) -> bufB (bf16)
  k_gemm_mfma<true><<<GEMM_BLOCKS, 256, 0, stream>>>(feat, wp1, bufA);
  k_agg<true><<<(N_NODES + 3) / 4, 256, 0, stream>>>(bufA, csr, rs, bufB);

  // layer 2: h2 = x1@W2 -> bufA (bf16); x2 = (h2+gather)/deg -> bufB ... -> readout
  k_gemm_mfma<false><<<GEMM_BLOCKS, 256, 0, stream>>>(bufB, wp2, bufA);
  k_agg<false><<<(N_NODES + 3) / 4, 256, 0, stream>>>(bufA, csr, rs, bufB);

  // readout + head
  k_readout<<<(N_NODES + 127) / 128, 128, 0, stream>>>(bufB, gid, gsum, gcnt);
  k_mlp<<<NUM_GRAPHS, 128, 0, stream>>>(gsum, gcnt, Wm, bm, out);
}

// Round 7
// 311.594 us; speedup vs baseline: 3.0714x; 1.0522x over previous
//
#include <hip/hip_runtime.h>

#define N_NODES 50000
#define N_EDGES 800000
#define NFEAT 128
#define NHID 128
#define NCLASS 10
#define NUM_GRAPHS 512
#define SCAN_NBLK 49       // ceil(50000/1024)
#define GEMM_BLOCKS 782    // ceil(50000/64)

// fused1 grid partition: [gemm1 | wpack | count]
#define G1_GEMM 782
#define G1_WPACK 8
#define G1_COUNT 1024
#define G1_GRID (G1_GEMM + G1_WPACK + G1_COUNT)

typedef __attribute__((ext_vector_type(8))) short bf16x8;
typedef __attribute__((ext_vector_type(4))) float f32x4;

__device__ inline ushort f2bf(float f) {
  union { float f; uint u; } c; c.f = f;
  return (ushort)((c.u + 0x7fffu + ((c.u >> 16) & 1u)) >> 16);
}
__device__ inline float bf2f_lo(uint u) { union { uint u; float f; } c; c.u = u << 16; return c.f; }
__device__ inline float bf2f_hi(uint u) { union { uint u; float f; } c; c.u = u & 0xffff0000u; return c.f; }
__device__ inline float bf2f_s(ushort h) { union { uint u; float f; } c; c.u = ((uint)h) << 16; return c.f; }

// ---------------- MFMA GEMM body: Y[bf16] = X @ Wp, 64-row tile ----------------
template <bool XFP32>
__device__ inline void gemm_body(const void* __restrict__ Xv,
                                 const ushort* __restrict__ Wp,
                                 ushort* __restrict__ Y,
                                 ushort* xs, ushort* wsh,
                                 int base, int tid) {
  const int rem = N_NODES - base;
  for (int i = tid; i < 2048; i += 256)
    ((uint4*)wsh)[i] = ((const uint4*)Wp)[i];

  for (int g = tid; g < 1024; g += 256) {
    int row = g >> 4;
    int k0 = (g & 15) << 3;
    int wt = row >> 4, ks = k0 >> 5;
    int lane = (row & 15) + (((k0 >> 3) & 3) << 4);
    uint4 v;
    if (row < rem) {
      if (XFP32) {
        const float* s = (const float*)Xv + (size_t)(base + row) * 128 + k0;
        float4 p0 = ((const float4*)s)[0];
        float4 p1 = ((const float4*)s)[1];
        v.x = (uint)f2bf(p0.x) | ((uint)f2bf(p0.y) << 16);
        v.y = (uint)f2bf(p0.z) | ((uint)f2bf(p0.w) << 16);
        v.z = (uint)f2bf(p1.x) | ((uint)f2bf(p1.y) << 16);
        v.w = (uint)f2bf(p1.z) | ((uint)f2bf(p1.w) << 16);
      } else {
        v = *(const uint4*)((const ushort*)Xv + (size_t)(base + row) * 128 + k0);
      }
    } else {
      v.x = 0; v.y = 0; v.z = 0; v.w = 0;
    }
    *(uint4*)&xs[((((wt << 2) + ks) << 6) + lane) << 3] = v;
  }
  __syncthreads();

  const int wave = tid >> 6, lane = tid & 63;
  f32x4 acc[8];
#pragma unroll
  for (int i = 0; i < 8; ++i) acc[i] = f32x4{0.f, 0.f, 0.f, 0.f};
  bf16x8 a[4];
#pragma unroll
  for (int ks = 0; ks < 4; ++ks)
    a[ks] = *(const bf16x8*)&xs[((((wave << 2) + ks) << 6) + lane) << 3];
#pragma unroll
  for (int ks = 0; ks < 4; ++ks) {
#pragma unroll
    for (int nt = 0; nt < 8; ++nt) {
      bf16x8 b = *(const bf16x8*)&wsh[((((nt << 2) + ks) << 6) + lane) << 3];
      acc[nt] = __builtin_amdgcn_mfma_f32_16x16x32_bf16(a[ks], b, acc[nt], 0, 0, 0);
    }
  }
  // C/D: col = lane&15, row = (lane>>4)*4 + reg
  const int r0 = base + wave * 16 + ((lane >> 4) << 2);
  const int c0 = lane & 15;
#pragma unroll
  for (int nt = 0; nt < 8; ++nt)
#pragma unroll
    for (int r = 0; r < 4; ++r) {
      int row = r0 + r;
      if (row < N_NODES)
        Y[(size_t)row * 128 + (nt << 4) + c0] = f2bf(acc[nt][r]);
    }
}

// ---------------- fused: gemm1 (feat@W1) + wpack(W1,W2) + count ----------------
__global__ __launch_bounds__(256) void k_fused1(const float* __restrict__ feat,
                                                const float* __restrict__ W1,
                                                const float* __restrict__ W2,
                                                ushort* __restrict__ wp1w,
                                                ushort* __restrict__ wp2w,
                                                const int* __restrict__ edst,
                                                int* __restrict__ cnt,
                                                ushort* __restrict__ Y) {
  __shared__ ushort xs[4 * 4 * 64 * 8];   // 16 KB
  __shared__ ushort wsh[32 * 64 * 8];     // 32 KB
  const int b = blockIdx.x;
  const int tid = threadIdx.x;
  if (b < G1_GEMM) {
    // gemm1 packs its own B-fragments from W1 directly into LDS (wp1 not yet ready).
    for (int idx = tid; idx < 16384; idx += 256) {
      int lane = (idx >> 3) & 63;
      int e = idx & 7;
      int frag = idx >> 9;
      int nt = frag >> 2, ks = frag & 3;
      int c = nt * 16 + (lane & 15);
      int k = ks * 32 + (lane >> 4) * 8 + e;
      wsh[idx] = f2bf(W1[k * 128 + c]);
    }
    const int base = b * 64;
    const int rem = N_NODES - base;
    for (int g = tid; g < 1024; g += 256) {
      int row = g >> 4;
      int k0 = (g & 15) << 3;
      int wt = row >> 4, ks = k0 >> 5;
      int lane = (row & 15) + (((k0 >> 3) & 3) << 4);
      uint4 v;
      if (row < rem) {
        const float* s = feat + (size_t)(base + row) * 128 + k0;
        float4 p0 = ((const float4*)s)[0];
        float4 p1 = ((const float4*)s)[1];
        v.x = (uint)f2bf(p0.x) | ((uint)f2bf(p0.y) << 16);
        v.y = (uint)f2bf(p0.z) | ((uint)f2bf(p0.w) << 16);
        v.z = (uint)f2bf(p1.x) | ((uint)f2bf(p1.y) << 16);
        v.w = (uint)f2bf(p1.z) | ((uint)f2bf(p1.w) << 16);
      } else {
        v.x = 0; v.y = 0; v.z = 0; v.w = 0;
      }
      *(uint4*)&xs[((((wt << 2) + ks) << 6) + lane) << 3] = v;
    }
    __syncthreads();
    const int wave = tid >> 6, lane = tid & 63;
    f32x4 acc[8];
#pragma unroll
    for (int i = 0; i < 8; ++i) acc[i] = f32x4{0.f, 0.f, 0.f, 0.f};
    bf16x8 a[4];
#pragma unroll
    for (int ks = 0; ks < 4; ++ks)
      a[ks] = *(const bf16x8*)&xs[((((wave << 2) + ks) << 6) + lane) << 3];
#pragma unroll
    for (int ks = 0; ks < 4; ++ks) {
#pragma unroll
      for (int nt = 0; nt < 8; ++nt) {
        bf16x8 bb = *(const bf16x8*)&wsh[((((nt << 2) + ks) << 6) + lane) << 3];
        acc[nt] = __builtin_amdgcn_mfma_f32_16x16x32_bf16(a[ks], bb, acc[nt], 0, 0, 0);
      }
    }
    const int r0 = base + wave * 16 + ((lane >> 4) << 2);
    const int c0 = lane & 15;
#pragma unroll
    for (int nt = 0; nt < 8; ++nt)
#pragma unroll
      for (int r = 0; r < 4; ++r) {
        int row = r0 + r;
        if (row < N_NODES)
          Y[(size_t)row * 128 + (nt << 4) + c0] = f2bf(acc[nt][r]);
      }
  } else if (b < G1_GEMM + G1_WPACK) {
    for (int idx = (b - G1_GEMM) * 256 + tid; idx < 32768; idx += G1_WPACK * 256) {
      const float* W = (idx < 16384) ? W1 : W2;
      ushort* op = (idx < 16384) ? wp1w : wp2w;
      int j = idx & 16383;
      int lane = (j >> 3) & 63;
      int e = j & 7;
      int frag = j >> 9;
      int nt = frag >> 2, ks = frag & 3;
      int c = nt * 16 + (lane & 15);
      int k = ks * 32 + (lane >> 4) * 8 + e;
      op[j] = f2bf(W[k * 128 + c]);
    }
  } else {
    for (int e = (b - G1_GEMM - G1_WPACK) * 256 + tid; e < N_EDGES;
         e += G1_COUNT * 256)
      atomicAdd(&cnt[edst[e]], 1);
  }
}

// ---------------- two-level scan ----------------
__global__ __launch_bounds__(1024) void k_scan1(const int* __restrict__ cnt,
                                                int* __restrict__ rs,
                                                int* __restrict__ bsum) {
  __shared__ int sdata[1024];
  const int tid = threadIdx.x;
  const int i = blockIdx.x * 1024 + tid;
  int v = (i < N_NODES) ? cnt[i] : 0;
  sdata[tid] = v;
  __syncthreads();
  for (int s = 1; s < 1024; s <<= 1) {
    int t = (tid >= s) ? sdata[tid - s] : 0;
    __syncthreads();
    sdata[tid] += t;
    __syncthreads();
  }
  if (i < N_NODES) rs[i] = sdata[tid] - v;  // local exclusive
  if (tid == 1023) bsum[blockIdx.x] = sdata[1023];
}

__global__ __launch_bounds__(64) void k_scan2(int* __restrict__ bsum,
                                              int* __restrict__ rs) {
  __shared__ int s[64];
  const int t = threadIdx.x;
  int v = (t < SCAN_NBLK) ? bsum[t] : 0;
  s[t] = v;
  __syncthreads();
  for (int d = 1; d < 64; d <<= 1) {
    int u = (t >= d) ? s[t - d] : 0;
    __syncthreads();
    s[t] += u;
    __syncthreads();
  }
  if (t < SCAN_NBLK) bsum[t] = s[t] - v;
  if (t == 0) rs[N_NODES] = N_EDGES;
}

// adds block offsets; also initializes cursor to absolute row start
__global__ __launch_bounds__(1024) void k_scan3(int* __restrict__ rs,
                                                const int* __restrict__ bsum,
                                                int* __restrict__ cursor) {
  const int i = blockIdx.x * 1024 + threadIdx.x;
  if (i < N_NODES) {
    int v = rs[i] + bsum[blockIdx.x];
    rs[i] = v;
    cursor[i] = v;
  }
}

// ---------------- bucket: csr16[p] = src (absolute cursor) ----------------
__global__ __launch_bounds__(256) void k_bucket(const int* __restrict__ src,
                                                const int* __restrict__ dst,
                                                int* __restrict__ cursor,
                                                ushort* __restrict__ csr16) {
  int e = blockIdx.x * 256 + threadIdx.x;
  if (e < N_EDGES) {
    int p = atomicAdd(&cursor[dst[e]], 1);
    csr16[p] = (ushort)src[e];
  }
}

// ---------------- gather-aggregate layer1 (bf16 rows, fp32 accumulate, relu) --------
__global__ __launch_bounds__(256) void k_agg1(const ushort* __restrict__ H,
                                              const ushort* __restrict__ csr16,
                                              const int* __restrict__ rs,
                                              ushort* __restrict__ Out) {
  const int node = blockIdx.x * 4 + (threadIdx.x >> 6);
  if (node >= N_NODES) return;
  const int lane = threadIdx.x & 63;
  const int beg = rs[node], end = rs[node + 1];
  const uint* __restrict__ H2 = (const uint*)H;
  float ax = 0.f, ay = 0.f;
  int e = beg;
  for (; e + 4 <= end; e += 4) {
    int s0 = csr16[e], s1 = csr16[e + 1], s2 = csr16[e + 2], s3 = csr16[e + 3];
    uint u0 = H2[(size_t)s0 * 64 + lane];
    uint u1 = H2[(size_t)s1 * 64 + lane];
    uint u2 = H2[(size_t)s2 * 64 + lane];
    uint u3 = H2[(size_t)s3 * 64 + lane];
    ax += (bf2f_lo(u0) + bf2f_lo(u1)) + (bf2f_lo(u2) + bf2f_lo(u3));
    ay += (bf2f_hi(u0) + bf2f_hi(u1)) + (bf2f_hi(u2) + bf2f_hi(u3));
  }
  for (; e < end; ++e) {
    uint u = H2[(size_t)csr16[e] * 64 + lane];
    ax += bf2f_lo(u);
    ay += bf2f_hi(u);
  }
  uint uh = H2[(size_t)node * 64 + lane];
  float inv = 1.0f / (float)(end - beg + 1);
  float rx = fmaxf((bf2f_lo(uh) + ax) * inv, 0.f);
  float ry = fmaxf((bf2f_hi(uh) + ay) * inv, 0.f);
  ((uint*)Out)[(size_t)node * 64 + lane] = (uint)f2bf(rx) | ((uint)f2bf(ry) << 16);
}

// ---------------- standalone gemm2 ----------------
__global__ __launch_bounds__(256) void k_gemm2(const ushort* __restrict__ X,
                                               const ushort* __restrict__ Wp,
                                               ushort* __restrict__ Y) {
  __shared__ ushort xs[4 * 4 * 64 * 8];
  __shared__ ushort wsh[32 * 64 * 8];
  gemm_body<false>(X, Wp, Y, xs, wsh, blockIdx.x * 64, threadIdx.x);
}

// ---------------- fused agg2 + per-graph readout (gid sorted) ----------------
__global__ __launch_bounds__(256) void k_agg_ro(const ushort* __restrict__ H,
                                                const ushort* __restrict__ csr16,
                                                const int* __restrict__ rs,
                                                const int* __restrict__ gid,
                                                float* __restrict__ gsum,
                                                float* __restrict__ gcnt) {
  __shared__ float rows[4][128];
  __shared__ int gids[4];
  const int w = threadIdx.x >> 6;
  const int lane = threadIdx.x & 63;
  const int node = blockIdx.x * 4 + w;  // 50000 = 12500*4 exact
  const int beg = rs[node], end = rs[node + 1];
  const uint* __restrict__ H2 = (const uint*)H;
  float ax = 0.f, ay = 0.f;
  int e = beg;
  for (; e + 4 <= end; e += 4) {
    int s0 = csr16[e], s1 = csr16[e + 1], s2 = csr16[e + 2], s3 = csr16[e + 3];
    uint u0 = H2[(size_t)s0 * 64 + lane];
    uint u1 = H2[(size_t)s1 * 64 + lane];
    uint u2 = H2[(size_t)s2 * 64 + lane];
    uint u3 = H2[(size_t)s3 * 64 + lane];
    ax += (bf2f_lo(u0) + bf2f_lo(u1)) + (bf2f_lo(u2) + bf2f_lo(u3));
    ay += (bf2f_hi(u0) + bf2f_hi(u1)) + (bf2f_hi(u2) + bf2f_hi(u3));
  }
  for (; e < end; ++e) {
    uint u = H2[(size_t)csr16[e] * 64 + lane];
    ax += bf2f_lo(u);
    ay += bf2f_hi(u);
  }
  uint uh = H2[(size_t)node * 64 + lane];
  float inv = 1.0f / (float)(end - beg + 1);
  // match round-4 numerics: x2 rounds through bf16 before the graph-mean.
  // (round-5/6 bug: bf2f_lo(f2bf(v) << 16) double-shifts -> 0; bf2f_s shifts once)
  float rx = bf2f_s(f2bf((bf2f_lo(uh) + ax) * inv));
  float ry = bf2f_s(f2bf((bf2f_hi(uh) + ay) * inv));
  *(float2*)&rows[w][lane * 2] = make_float2(rx, ry);
  if (lane == 0) gids[w] = gid[node];
  __syncthreads();
  const int t = threadIdx.x;
  if (t < 128) {
    float acc = rows[0][t];
    int g = gids[0];
#pragma unroll
    for (int r = 1; r < 4; ++r) {
      int gr = gids[r];
      if (gr != g) {
        atomicAdd(&gsum[g * 128 + t], acc);
        acc = 0.f;
        g = gr;
      }
      acc += rows[r][t];
    }
    atomicAdd(&gsum[g * 128 + t], acc);
  } else if (t == 128) {
    float c = 1.f;
    int g = gids[0];
#pragma unroll
    for (int r = 1; r < 4; ++r) {
      int gr = gids[r];
      if (gr != g) {
        atomicAdd(&gcnt[g], c);
        c = 0.f;
        g = gr;
      }
      c += 1.f;
    }
    atomicAdd(&gcnt[g], c);
  }
}

// ---------------- gmean @ mlp_w + b, log_softmax ----------------
__global__ __launch_bounds__(128) void k_mlp(const float* __restrict__ gsum,
                                             const float* __restrict__ gcnt,
                                             const float* __restrict__ Wm,
                                             const float* __restrict__ bm,
                                             float* __restrict__ out) {
  __shared__ float m[128];
  __shared__ float lg[NCLASS];
  const int g = blockIdx.x;
  const int t = threadIdx.x;
  float cnt = fmaxf(gcnt[g], 1.0f);
  m[t] = gsum[g * 128 + t] / cnt;
  __syncthreads();
  if (t < NCLASS) {
    float s = bm[t];
#pragma unroll
    for (int k = 0; k < 128; ++k) s += m[k] * Wm[k * NCLASS + t];
    lg[t] = s;
  }
  __syncthreads();
  if (t < NCLASS) {
    float mx = lg[0];
#pragma unroll
    for (int i = 1; i < NCLASS; ++i) mx = fmaxf(mx, lg[i]);
    float sum = 0.f;
#pragma unroll
    for (int i = 0; i < NCLASS; ++i) sum += expf(lg[i] - mx);
    out[g * NCLASS + t] = lg[t] - mx - logf(sum);
  }
}

extern "C" void kernel_launch(void* const* d_in, const int* in_sizes, int n_in,
                              void* d_out, int out_size, void* d_ws, size_t ws_size,
                              hipStream_t stream) {
  const float* feat = (const float*)d_in[0];
  const float* W1   = (const float*)d_in[1];
  const float* W2   = (const float*)d_in[2];
  const float* Wm   = (const float*)d_in[3];
  const float* bm   = (const float*)d_in[4];
  const int* esrc   = (const int*)d_in[5];
  const int* edst   = (const int*)d_in[6];
  const int* gid    = (const int*)d_in[7];
  float* out = (float*)d_out;

  // workspace layout:
  // ints:   cnt[50048] | cursor[50048] | rs[50056] | bsum[64]
  // ushort: csr16[800000] | wp1[16384] | wp2[16384] | bufA[6.4M] | bufB[6.4M]
  // float:  gsum[512*128] | gcnt[512]
  int* cnt      = (int*)d_ws;
  int* cursor   = cnt + 50048;
  int* rs       = cursor + 50048;
  int* bsum     = rs + 50056;
  ushort* csr16 = (ushort*)(bsum + 64);
  ushort* wp1   = csr16 + 800000;
  ushort* wp2   = wp1 + 16384;
  ushort* bufA  = wp2 + 16384;
  ushort* bufB  = bufA + (size_t)N_NODES * NHID;
  float* gsum   = (float*)(bufB + (size_t)N_NODES * NHID);
  float* gcnt   = gsum + NUM_GRAPHS * NHID;

  hipMemsetAsync(cnt, 0, (size_t)50048 * sizeof(int), stream);
  hipMemsetAsync(gsum, 0, (size_t)(NUM_GRAPHS * NHID + 512) * sizeof(float), stream);

  // fused: gemm1 (feat@W1 -> bufA bf16) + wpack(W1,W2) + deg-count
  k_fused1<<<G1_GRID, 256, 0, stream>>>(feat, W1, W2, wp1, wp2, edst, cnt, bufA);

  // scans (cursor := rs in scan3)
  k_scan1<<<SCAN_NBLK, 1024, 0, stream>>>(cnt, rs, bsum);
  k_scan2<<<1, 64, 0, stream>>>(bsum, rs);
  k_scan3<<<SCAN_NBLK, 1024, 0, stream>>>(rs, bsum, cursor);
  k_bucket<<<(N_EDGES + 255) / 256, 256, 0, stream>>>(esrc, edst, cursor, csr16);

  // x1 = relu((h1+gather)/deg) -> bufB (bf16)
  k_agg1<<<(N_NODES + 3) / 4, 256, 0, stream>>>(bufA, csr16, rs, bufB);

  // h2 = x1@W2 -> bufA (bf16)
  k_gemm2<<<GEMM_BLOCKS, 256, 0, stream>>>(bufB, wp2, bufA);

  // x2 = (h2+gather)/deg fused with per-graph sum readout
  k_agg_ro<<<N_NODES / 4, 256, 0, stream>>>(bufA, csr16, rs, gid, gsum, gcnt);

  k_mlp<<<NUM_GRAPHS, 128, 0, stream>>>(gsum, gcnt, Wm, bm, out);
}

// Round 8
// 261.429 us; speedup vs baseline: 3.6608x; 1.1919x over previous
//
#include <hip/hip_runtime.h>

#define N_NODES 50000
#define N_EDGES 800000
#define NFEAT 128
#define NHID 128
#define NCLASS 10
#define NUM_GRAPHS 512
#define GEMM_BLOCKS 782    // ceil(50000/64)
#define SLOT 64            // per-node CSR capacity (Poisson mean 16)

// fused1 grid partition: [gemm1 | bucket]
#define G1_GEMM 782
#define G1_BKT 1024
#define G1_GRID (G1_GEMM + G1_BKT)

typedef __attribute__((ext_vector_type(8))) short bf16x8;
typedef __attribute__((ext_vector_type(4))) float f32x4;

__device__ inline ushort f2bf(float f) {
  union { float f; uint u; } c; c.f = f;
  return (ushort)((c.u + 0x7fffu + ((c.u >> 16) & 1u)) >> 16);
}
__device__ inline float bf2f_lo(uint u) { union { uint u; float f; } c; c.u = u << 16; return c.f; }
__device__ inline float bf2f_hi(uint u) { union { uint u; float f; } c; c.u = u & 0xffff0000u; return c.f; }
__device__ inline float bf2f_s(ushort h) { union { uint u; float f; } c; c.u = ((uint)h) << 16; return c.f; }

// ---------------- MFMA GEMM body: Y[bf16] = X @ Wp, 64-row tile ----------------
template <bool XFP32>
__device__ inline void gemm_body(const void* __restrict__ Xv,
                                 const ushort* __restrict__ Wp,
                                 ushort* __restrict__ Y,
                                 ushort* xs, ushort* wsh,
                                 int base, int tid) {
  const int rem = N_NODES - base;
  for (int i = tid; i < 2048; i += 256)
    ((uint4*)wsh)[i] = ((const uint4*)Wp)[i];

  for (int g = tid; g < 1024; g += 256) {
    int row = g >> 4;
    int k0 = (g & 15) << 3;
    int wt = row >> 4, ks = k0 >> 5;
    int lane = (row & 15) + (((k0 >> 3) & 3) << 4);
    uint4 v;
    if (row < rem) {
      if (XFP32) {
        const float* s = (const float*)Xv + (size_t)(base + row) * 128 + k0;
        float4 p0 = ((const float4*)s)[0];
        float4 p1 = ((const float4*)s)[1];
        v.x = (uint)f2bf(p0.x) | ((uint)f2bf(p0.y) << 16);
        v.y = (uint)f2bf(p0.z) | ((uint)f2bf(p0.w) << 16);
        v.z = (uint)f2bf(p1.x) | ((uint)f2bf(p1.y) << 16);
        v.w = (uint)f2bf(p1.z) | ((uint)f2bf(p1.w) << 16);
      } else {
        v = *(const uint4*)((const ushort*)Xv + (size_t)(base + row) * 128 + k0);
      }
    } else {
      v.x = 0; v.y = 0; v.z = 0; v.w = 0;
    }
    *(uint4*)&xs[((((wt << 2) + ks) << 6) + lane) << 3] = v;
  }
  __syncthreads();

  const int wave = tid >> 6, lane = tid & 63;
  f32x4 acc[8];
#pragma unroll
  for (int i = 0; i < 8; ++i) acc[i] = f32x4{0.f, 0.f, 0.f, 0.f};
  bf16x8 a[4];
#pragma unroll
  for (int ks = 0; ks < 4; ++ks)
    a[ks] = *(const bf16x8*)&xs[((((wave << 2) + ks) << 6) + lane) << 3];
#pragma unroll
  for (int ks = 0; ks < 4; ++ks) {
#pragma unroll
    for (int nt = 0; nt < 8; ++nt) {
      bf16x8 b = *(const bf16x8*)&wsh[((((nt << 2) + ks) << 6) + lane) << 3];
      acc[nt] = __builtin_amdgcn_mfma_f32_16x16x32_bf16(a[ks], b, acc[nt], 0, 0, 0);
    }
  }
  // C/D: col = lane&15, row = (lane>>4)*4 + reg
  const int r0 = base + wave * 16 + ((lane >> 4) << 2);
  const int c0 = lane & 15;
#pragma unroll
  for (int nt = 0; nt < 8; ++nt)
#pragma unroll
    for (int r = 0; r < 4; ++r) {
      int row = r0 + r;
      if (row < N_NODES)
        Y[(size_t)row * 128 + (nt << 4) + c0] = f2bf(acc[nt][r]);
    }
}

// ---------------- W pre-pack (both weights in one launch; 128 blocks) ----------------
__global__ __launch_bounds__(256) void k_wpack(const float* __restrict__ W1,
                                               const float* __restrict__ W2,
                                               ushort* __restrict__ wp1,
                                               ushort* __restrict__ wp2) {
  int idx = blockIdx.x * 256 + threadIdx.x;  // 0..32767
  const float* W = (idx < 16384) ? W1 : W2;
  ushort* op = (idx < 16384) ? wp1 : wp2;
  int j = idx & 16383;
  int lane = (j >> 3) & 63;
  int e = j & 7;
  int frag = j >> 9;
  int nt = frag >> 2, ks = frag & 3;
  int c = nt * 16 + (lane & 15);
  int k = ks * 32 + (lane >> 4) * 8 + e;
  op[j] = f2bf(W[k * 128 + c]);
}

// ---------------- fused: gemm1 (feat@W1, pre-packed wp1) + slot-CSR bucket ------------
__global__ __launch_bounds__(256) void k_fused1(const float* __restrict__ feat,
                                                const ushort* __restrict__ wp1,
                                                const int* __restrict__ esrc,
                                                const int* __restrict__ edst,
                                                int* __restrict__ cnt,
                                                ushort* __restrict__ csr16,
                                                ushort* __restrict__ Y) {
  __shared__ ushort xs[4 * 4 * 64 * 8];   // 16 KB
  __shared__ ushort wsh[32 * 64 * 8];     // 32 KB
  const int b = blockIdx.x;
  const int tid = threadIdx.x;
  if (b < G1_GEMM) {
    gemm_body<true>(feat, wp1, Y, xs, wsh, b * 64, tid);
  } else {
    for (int e = (b - G1_GEMM) * 256 + tid; e < N_EDGES; e += G1_BKT * 256) {
      int d = edst[e];
      int p = atomicAdd(&cnt[d], 1);
      if (p < SLOT) csr16[(size_t)d * SLOT + p] = (ushort)esrc[e];
    }
  }
}

// ---------------- gather-aggregate layer1 (slot-CSR, 8-deep MLP) ----------------
__global__ __launch_bounds__(256) void k_agg1(const ushort* __restrict__ H,
                                              const ushort* __restrict__ csr16,
                                              const int* __restrict__ cnt,
                                              ushort* __restrict__ Out) {
  const int node = blockIdx.x * 4 + (threadIdx.x >> 6);  // 50000 = 12500*4 exact
  const int lane = threadIdx.x & 63;
  const int deg = min(cnt[node], SLOT);
  const ushort* nb = csr16 + (size_t)node * SLOT;
  const uint* __restrict__ H2 = (const uint*)H;
  float ax = 0.f, ay = 0.f;
  int e = 0;
  for (; e + 8 <= deg; e += 8) {
    uint4 iv = *(const uint4*)(nb + e);
    uint s0 = iv.x & 0xffffu, s1 = iv.x >> 16, s2 = iv.y & 0xffffu, s3 = iv.y >> 16;
    uint s4 = iv.z & 0xffffu, s5 = iv.z >> 16, s6 = iv.w & 0xffffu, s7 = iv.w >> 16;
    uint u0 = H2[(size_t)s0 * 64 + lane];
    uint u1 = H2[(size_t)s1 * 64 + lane];
    uint u2 = H2[(size_t)s2 * 64 + lane];
    uint u3 = H2[(size_t)s3 * 64 + lane];
    uint u4 = H2[(size_t)s4 * 64 + lane];
    uint u5 = H2[(size_t)s5 * 64 + lane];
    uint u6 = H2[(size_t)s6 * 64 + lane];
    uint u7 = H2[(size_t)s7 * 64 + lane];
    ax += ((bf2f_lo(u0) + bf2f_lo(u1)) + (bf2f_lo(u2) + bf2f_lo(u3))) +
          ((bf2f_lo(u4) + bf2f_lo(u5)) + (bf2f_lo(u6) + bf2f_lo(u7)));
    ay += ((bf2f_hi(u0) + bf2f_hi(u1)) + (bf2f_hi(u2) + bf2f_hi(u3))) +
          ((bf2f_hi(u4) + bf2f_hi(u5)) + (bf2f_hi(u6) + bf2f_hi(u7)));
  }
  if (e + 4 <= deg) {
    uint2 iv = *(const uint2*)(nb + e);
    uint s0 = iv.x & 0xffffu, s1 = iv.x >> 16, s2 = iv.y & 0xffffu, s3 = iv.y >> 16;
    uint u0 = H2[(size_t)s0 * 64 + lane];
    uint u1 = H2[(size_t)s1 * 64 + lane];
    uint u2 = H2[(size_t)s2 * 64 + lane];
    uint u3 = H2[(size_t)s3 * 64 + lane];
    ax += (bf2f_lo(u0) + bf2f_lo(u1)) + (bf2f_lo(u2) + bf2f_lo(u3));
    ay += (bf2f_hi(u0) + bf2f_hi(u1)) + (bf2f_hi(u2) + bf2f_hi(u3));
    e += 4;
  }
  for (; e < deg; ++e) {
    uint u = H2[(size_t)nb[e] * 64 + lane];
    ax += bf2f_lo(u);
    ay += bf2f_hi(u);
  }
  uint uh = H2[(size_t)node * 64 + lane];
  float inv = 1.0f / (float)(deg + 1);
  float rx = fmaxf((bf2f_lo(uh) + ax) * inv, 0.f);
  float ry = fmaxf((bf2f_hi(uh) + ay) * inv, 0.f);
  ((uint*)Out)[(size_t)node * 64 + lane] = (uint)f2bf(rx) | ((uint)f2bf(ry) << 16);
}

// ---------------- standalone gemm2 ----------------
__global__ __launch_bounds__(256) void k_gemm2(const ushort* __restrict__ X,
                                               const ushort* __restrict__ Wp,
                                               ushort* __restrict__ Y) {
  __shared__ ushort xs[4 * 4 * 64 * 8];
  __shared__ ushort wsh[32 * 64 * 8];
  gemm_body<false>(X, Wp, Y, xs, wsh, blockIdx.x * 64, threadIdx.x);
}

// ---------------- fused agg2 + per-graph readout (gid sorted) ----------------
__global__ __launch_bounds__(256) void k_agg_ro(const ushort* __restrict__ H,
                                                const ushort* __restrict__ csr16,
                                                const int* __restrict__ cnt,
                                                const int* __restrict__ gid,
                                                float* __restrict__ gsum,
                                                float* __restrict__ gcnt) {
  __shared__ float rows[4][128];
  __shared__ int gids[4];
  const int w = threadIdx.x >> 6;
  const int lane = threadIdx.x & 63;
  const int node = blockIdx.x * 4 + w;  // exact
  const int deg = min(cnt[node], SLOT);
  const ushort* nb = csr16 + (size_t)node * SLOT;
  const uint* __restrict__ H2 = (const uint*)H;
  float ax = 0.f, ay = 0.f;
  int e = 0;
  for (; e + 8 <= deg; e += 8) {
    uint4 iv = *(const uint4*)(nb + e);
    uint s0 = iv.x & 0xffffu, s1 = iv.x >> 16, s2 = iv.y & 0xffffu, s3 = iv.y >> 16;
    uint s4 = iv.z & 0xffffu, s5 = iv.z >> 16, s6 = iv.w & 0xffffu, s7 = iv.w >> 16;
    uint u0 = H2[(size_t)s0 * 64 + lane];
    uint u1 = H2[(size_t)s1 * 64 + lane];
    uint u2 = H2[(size_t)s2 * 64 + lane];
    uint u3 = H2[(size_t)s3 * 64 + lane];
    uint u4 = H2[(size_t)s4 * 64 + lane];
    uint u5 = H2[(size_t)s5 * 64 + lane];
    uint u6 = H2[(size_t)s6 * 64 + lane];
    uint u7 = H2[(size_t)s7 * 64 + lane];
    ax += ((bf2f_lo(u0) + bf2f_lo(u1)) + (bf2f_lo(u2) + bf2f_lo(u3))) +
          ((bf2f_lo(u4) + bf2f_lo(u5)) + (bf2f_lo(u6) + bf2f_lo(u7)));
    ay += ((bf2f_hi(u0) + bf2f_hi(u1)) + (bf2f_hi(u2) + bf2f_hi(u3))) +
          ((bf2f_hi(u4) + bf2f_hi(u5)) + (bf2f_hi(u6) + bf2f_hi(u7)));
  }
  if (e + 4 <= deg) {
    uint2 iv = *(const uint2*)(nb + e);
    uint s0 = iv.x & 0xffffu, s1 = iv.x >> 16, s2 = iv.y & 0xffffu, s3 = iv.y >> 16;
    uint u0 = H2[(size_t)s0 * 64 + lane];
    uint u1 = H2[(size_t)s1 * 64 + lane];
    uint u2 = H2[(size_t)s2 * 64 + lane];
    uint u3 = H2[(size_t)s3 * 64 + lane];
    ax += (bf2f_lo(u0) + bf2f_lo(u1)) + (bf2f_lo(u2) + bf2f_lo(u3));
    ay += (bf2f_hi(u0) + bf2f_hi(u1)) + (bf2f_hi(u2) + bf2f_hi(u3));
    e += 4;
  }
  for (; e < deg; ++e) {
    uint u = H2[(size_t)nb[e] * 64 + lane];
    ax += bf2f_lo(u);
    ay += bf2f_hi(u);
  }
  uint uh = H2[(size_t)node * 64 + lane];
  float inv = 1.0f / (float)(deg + 1);
  // x2 rounds through bf16 before the graph-mean (bf2f_s: single shift)
  float rx = bf2f_s(f2bf((bf2f_lo(uh) + ax) * inv));
  float ry = bf2f_s(f2bf((bf2f_hi(uh) + ay) * inv));
  *(float2*)&rows[w][lane * 2] = make_float2(rx, ry);
  if (lane == 0) gids[w] = gid[node];
  __syncthreads();
  const int t = threadIdx.x;
  if (t < 128) {
    float acc = rows[0][t];
    int g = gids[0];
#pragma unroll
    for (int r = 1; r < 4; ++r) {
      int gr = gids[r];
      if (gr != g) {
        atomicAdd(&gsum[g * 128 + t], acc);
        acc = 0.f;
        g = gr;
      }
      acc += rows[r][t];
    }
    atomicAdd(&gsum[g * 128 + t], acc);
  } else if (t == 128) {
    float c = 1.f;
    int g = gids[0];
#pragma unroll
    for (int r = 1; r < 4; ++r) {
      int gr = gids[r];
      if (gr != g) {
        atomicAdd(&gcnt[g], c);
        c = 0.f;
        g = gr;
      }
      c += 1.f;
    }
    atomicAdd(&gcnt[g], c);
  }
}

// ---------------- gmean @ mlp_w + b, log_softmax ----------------
__global__ __launch_bounds__(128) void k_mlp(const float* __restrict__ gsum,
                                             const float* __restrict__ gcnt,
                                             const float* __restrict__ Wm,
                                             const float* __restrict__ bm,
                                             float* __restrict__ out) {
  __shared__ float m[128];
  __shared__ float lg[NCLASS];
  const int g = blockIdx.x;
  const int t = threadIdx.x;
  float cnt = fmaxf(gcnt[g], 1.0f);
  m[t] = gsum[g * 128 + t] / cnt;
  __syncthreads();
  if (t < NCLASS) {
    float s = bm[t];
#pragma unroll
    for (int k = 0; k < 128; ++k) s += m[k] * Wm[k * NCLASS + t];
    lg[t] = s;
  }
  __syncthreads();
  if (t < NCLASS) {
    float mx = lg[0];
#pragma unroll
    for (int i = 1; i < NCLASS; ++i) mx = fmaxf(mx, lg[i]);
    float sum = 0.f;
#pragma unroll
    for (int i = 0; i < NCLASS; ++i) sum += expf(lg[i] - mx);
    out[g * NCLASS + t] = lg[t] - mx - logf(sum);
  }
}

extern "C" void kernel_launch(void* const* d_in, const int* in_sizes, int n_in,
                              void* d_out, int out_size, void* d_ws, size_t ws_size,
                              hipStream_t stream) {
  const float* feat = (const float*)d_in[0];
  const float* W1   = (const float*)d_in[1];
  const float* W2   = (const float*)d_in[2];
  const float* Wm   = (const float*)d_in[3];
  const float* bm   = (const float*)d_in[4];
  const int* esrc   = (const int*)d_in[5];
  const int* edst   = (const int*)d_in[6];
  const int* gid    = (const int*)d_in[7];
  float* out = (float*)d_out;

  // workspace layout:
  // ints:   cnt[50048]
  // ushort: csr16[50000*64] | wp1[16384] | wp2[16384] | bufA[6.4M] | bufB[6.4M]
  // float:  gsum[512*128] | gcnt[512]
  int* cnt      = (int*)d_ws;
  ushort* csr16 = (ushort*)(cnt + 50048);
  ushort* wp1   = csr16 + (size_t)N_NODES * SLOT;
  ushort* wp2   = wp1 + 16384;
  ushort* bufA  = wp2 + 16384;
  ushort* bufB  = bufA + (size_t)N_NODES * NHID;
  float* gsum   = (float*)(bufB + (size_t)N_NODES * NHID);
  float* gcnt   = gsum + NUM_GRAPHS * NHID;

  hipMemsetAsync(cnt, 0, (size_t)50048 * sizeof(int), stream);
  hipMemsetAsync(gsum, 0, (size_t)(NUM_GRAPHS * NHID + 512) * sizeof(float), stream);

  // pack W1,W2 into MFMA B-fragment order (tiny)
  k_wpack<<<128, 256, 0, stream>>>(W1, W2, wp1, wp2);

  // fused: gemm1 (feat@W1 -> bufA bf16) + slot-CSR bucket (cnt + csr16)
  k_fused1<<<G1_GRID, 256, 0, stream>>>(feat, wp1, esrc, edst, cnt, csr16, bufA);

  // x1 = relu((h1+gather)/deg) -> bufB (bf16)
  k_agg1<<<N_NODES / 4, 256, 0, stream>>>(bufA, csr16, cnt, bufB);

  // h2 = x1@W2 -> bufA (bf16)
  k_gemm2<<<GEMM_BLOCKS, 256, 0, stream>>>(bufB, wp2, bufA);

  // x2 = (h2+gather)/deg fused with per-graph sum readout
  k_agg_ro<<<N_NODES / 4, 256, 0, stream>>>(bufA, csr16, cnt, gid, gsum, gcnt);

  k_mlp<<<NUM_GRAPHS, 128, 0, stream>>>(gsum, gcnt, Wm, bm, out);
}

// Round 9
// 232.073 us; speedup vs baseline: 4.1239x; 1.1265x over previous
//
#include <hip/hip_runtime.h>

#define N_NODES 50000
#define N_EDGES 800000
#define NFEAT 128
#define NHID 128
#define NCLASS 10
#define NUM_GRAPHS 512
#define GEMM_BLOCKS 782    // ceil(50000/64)
#define SLOT 64            // per-node CSR capacity (Poisson mean 16; P(>64) ~ 1e-18)
#define NSLICE 6250        // N_NODES / 8 (dst range per XCD group)

// fused1 grid partition: [gemm1 | bucket]
#define G1_GEMM 782
#define G1_BKT 1024        // 8 groups x 128 blocks
#define G1_GRID (G1_GEMM + G1_BKT)

typedef __attribute__((ext_vector_type(8))) short bf16x8;
typedef __attribute__((ext_vector_type(4))) float f32x4;

__device__ inline ushort f2bf(float f) {
  union { float f; uint u; } c; c.f = f;
  return (ushort)((c.u + 0x7fffu + ((c.u >> 16) & 1u)) >> 16);
}
__device__ inline float bf2f_lo(uint u) { union { uint u; float f; } c; c.u = u << 16; return c.f; }
__device__ inline float bf2f_hi(uint u) { union { uint u; float f; } c; c.u = u & 0xffff0000u; return c.f; }
__device__ inline float bf2f_s(ushort h) { union { uint u; float f; } c; c.u = ((uint)h) << 16; return c.f; }

// ---------------- MFMA GEMM body: Y[bf16] = X @ Wp, 64-row tile ----------------
template <bool XFP32>
__device__ inline void gemm_body(const void* __restrict__ Xv,
                                 const ushort* __restrict__ Wp,
                                 ushort* __restrict__ Y,
                                 ushort* xs, ushort* wsh,
                                 int base, int tid) {
  const int rem = N_NODES - base;
  for (int i = tid; i < 2048; i += 256)
    ((uint4*)wsh)[i] = ((const uint4*)Wp)[i];

  for (int g = tid; g < 1024; g += 256) {
    int row = g >> 4;
    int k0 = (g & 15) << 3;
    int wt = row >> 4, ks = k0 >> 5;
    int lane = (row & 15) + (((k0 >> 3) & 3) << 4);
    uint4 v;
    if (row < rem) {
      if (XFP32) {
        const float* s = (const float*)Xv + (size_t)(base + row) * 128 + k0;
        float4 p0 = ((const float4*)s)[0];
        float4 p1 = ((const float4*)s)[1];
        v.x = (uint)f2bf(p0.x) | ((uint)f2bf(p0.y) << 16);
        v.y = (uint)f2bf(p0.z) | ((uint)f2bf(p0.w) << 16);
        v.z = (uint)f2bf(p1.x) | ((uint)f2bf(p1.y) << 16);
        v.w = (uint)f2bf(p1.z) | ((uint)f2bf(p1.w) << 16);
      } else {
        v = *(const uint4*)((const ushort*)Xv + (size_t)(base + row) * 128 + k0);
      }
    } else {
      v.x = 0; v.y = 0; v.z = 0; v.w = 0;
    }
    *(uint4*)&xs[((((wt << 2) + ks) << 6) + lane) << 3] = v;
  }
  __syncthreads();

  const int wave = tid >> 6, lane = tid & 63;
  f32x4 acc[8];
#pragma unroll
  for (int i = 0; i < 8; ++i) acc[i] = f32x4{0.f, 0.f, 0.f, 0.f};
  bf16x8 a[4];
#pragma unroll
  for (int ks = 0; ks < 4; ++ks)
    a[ks] = *(const bf16x8*)&xs[((((wave << 2) + ks) << 6) + lane) << 3];
#pragma unroll
  for (int ks = 0; ks < 4; ++ks) {
#pragma unroll
    for (int nt = 0; nt < 8; ++nt) {
      bf16x8 b = *(const bf16x8*)&wsh[((((nt << 2) + ks) << 6) + lane) << 3];
      acc[nt] = __builtin_amdgcn_mfma_f32_16x16x32_bf16(a[ks], b, acc[nt], 0, 0, 0);
    }
  }
  // C/D: col = lane&15, row = (lane>>4)*4 + reg
  const int r0 = base + wave * 16 + ((lane >> 4) << 2);
  const int c0 = lane & 15;
#pragma unroll
  for (int nt = 0; nt < 8; ++nt)
#pragma unroll
    for (int r = 0; r < 4; ++r) {
      int row = r0 + r;
      if (row < N_NODES)
        Y[(size_t)row * 128 + (nt << 4) + c0] = f2bf(acc[nt][r]);
    }
}

// ---------------- W pre-pack (both weights; 128 blocks) ----------------
__global__ __launch_bounds__(256) void k_wpack(const float* __restrict__ W1,
                                               const float* __restrict__ W2,
                                               ushort* __restrict__ wp1,
                                               ushort* __restrict__ wp2) {
  int idx = blockIdx.x * 256 + threadIdx.x;  // 0..32767
  const float* W = (idx < 16384) ? W1 : W2;
  ushort* op = (idx < 16384) ? wp1 : wp2;
  int j = idx & 16383;
  int lane = (j >> 3) & 63;
  int e = j & 7;
  int frag = j >> 9;
  int nt = frag >> 2, ks = frag & 3;
  int c = nt * 16 + (lane & 15);
  int k = ks * 32 + (lane >> 4) * 8 + e;
  op[j] = f2bf(W[k * 128 + c]);
}

// ---------------- fused: gemm1 + XCD-sliced slot-CSR bucket ----------------
// Bucket: group g = blockIdx&7 (~XCD id) handles dst in [g*6250,(g+1)*6250) only.
// All atomics/stores of a group land in an 800KB L2-resident slice -> no
// cross-XCD line ping-pong. Each group streams the full edge list (8x edst read).
__global__ __launch_bounds__(256) void k_fused1(const float* __restrict__ feat,
                                                const ushort* __restrict__ wp1,
                                                const int* __restrict__ esrc,
                                                const int* __restrict__ edst,
                                                int* __restrict__ cnt,
                                                ushort* __restrict__ csr16,
                                                ushort* __restrict__ Y) {
  __shared__ ushort xs[4 * 4 * 64 * 8];   // 16 KB
  __shared__ ushort wsh[32 * 64 * 8];     // 32 KB
  const int b = blockIdx.x;
  const int tid = threadIdx.x;
  if (b < G1_GEMM) {
    gemm_body<true>(feat, wp1, Y, xs, wsh, b * 64, tid);
  } else {
    const int g = b & 7;                      // XCD-aligned dst-slice
    const int m = (b - G1_GEMM) >> 3;         // 0..127 within group (exact cover)
    const int lo = g * NSLICE, hi = lo + NSLICE;
    for (int e = m * 256 + tid; e < N_EDGES; e += 128 * 256) {
      int d = edst[e];
      if (d >= lo && d < hi) {
        int p = atomicAdd(&cnt[d], 1);
        if (p < SLOT) csr16[(size_t)d * SLOT + p] = (ushort)esrc[e];
      }
    }
  }
}

// ---------------- half-wave gather: 32 lanes x uint2 = one 256B row ----------------
__device__ inline void unpack_add(uint2 u, float4& a) {
  a.x += bf2f_lo(u.x); a.y += bf2f_hi(u.x);
  a.z += bf2f_lo(u.y); a.w += bf2f_hi(u.y);
}

__device__ inline float4 gather_sum(const uint2* __restrict__ Hv,
                                    const ushort* __restrict__ nb,
                                    int deg, int q) {
  float4 a = {0.f, 0.f, 0.f, 0.f};
  int e = 0;
  for (; e + 8 <= deg; e += 8) {
    uint4 iv = *(const uint4*)(nb + e);  // half-wave-uniform 16B
    uint2 u0 = Hv[(size_t)(iv.x & 0xffffu) * 32 + q];
    uint2 u1 = Hv[(size_t)(iv.x >> 16) * 32 + q];
    uint2 u2 = Hv[(size_t)(iv.y & 0xffffu) * 32 + q];
    uint2 u3 = Hv[(size_t)(iv.y >> 16) * 32 + q];
    uint2 u4 = Hv[(size_t)(iv.z & 0xffffu) * 32 + q];
    uint2 u5 = Hv[(size_t)(iv.z >> 16) * 32 + q];
    uint2 u6 = Hv[(size_t)(iv.w & 0xffffu) * 32 + q];
    uint2 u7 = Hv[(size_t)(iv.w >> 16) * 32 + q];
    unpack_add(u0, a); unpack_add(u1, a); unpack_add(u2, a); unpack_add(u3, a);
    unpack_add(u4, a); unpack_add(u5, a); unpack_add(u6, a); unpack_add(u7, a);
  }
  if (e + 4 <= deg) {
    uint2 iv = *(const uint2*)(nb + e);
    uint2 u0 = Hv[(size_t)(iv.x & 0xffffu) * 32 + q];
    uint2 u1 = Hv[(size_t)(iv.x >> 16) * 32 + q];
    uint2 u2 = Hv[(size_t)(iv.y & 0xffffu) * 32 + q];
    uint2 u3 = Hv[(size_t)(iv.y >> 16) * 32 + q];
    unpack_add(u0, a); unpack_add(u1, a); unpack_add(u2, a); unpack_add(u3, a);
    e += 4;
  }
  for (; e < deg; ++e) {
    uint2 u = Hv[(size_t)nb[e] * 32 + q];
    unpack_add(u, a);
  }
  return a;
}

// ---------------- agg layer1: 8 nodes/block (4 waves x 2 half-waves) ----------------
__global__ __launch_bounds__(256) void k_agg1(const ushort* __restrict__ H,
                                              const ushort* __restrict__ csr16,
                                              const int* __restrict__ cnt,
                                              ushort* __restrict__ Out) {
  const int w = threadIdx.x >> 6;
  const int l = threadIdx.x & 63;
  const int h = l >> 5, q = l & 31;
  const int node = blockIdx.x * 8 + w * 2 + h;  // 50000 = 6250*8 exact
  const int deg = min(cnt[node], SLOT);
  const ushort* nb = csr16 + (size_t)node * SLOT;
  const uint2* __restrict__ Hv = (const uint2*)H;
  float4 a = gather_sum(Hv, nb, deg, q);
  uint2 uh = Hv[(size_t)node * 32 + q];
  float inv = 1.0f / (float)(deg + 1);
  float r0 = fmaxf((bf2f_lo(uh.x) + a.x) * inv, 0.f);
  float r1 = fmaxf((bf2f_hi(uh.x) + a.y) * inv, 0.f);
  float r2 = fmaxf((bf2f_lo(uh.y) + a.z) * inv, 0.f);
  float r3 = fmaxf((bf2f_hi(uh.y) + a.w) * inv, 0.f);
  uint2 ov;
  ov.x = (uint)f2bf(r0) | ((uint)f2bf(r1) << 16);
  ov.y = (uint)f2bf(r2) | ((uint)f2bf(r3) << 16);
  ((uint2*)Out)[(size_t)node * 32 + q] = ov;
}

// ---------------- standalone gemm2 ----------------
__global__ __launch_bounds__(256) void k_gemm2(const ushort* __restrict__ X,
                                               const ushort* __restrict__ Wp,
                                               ushort* __restrict__ Y) {
  __shared__ ushort xs[4 * 4 * 64 * 8];
  __shared__ ushort wsh[32 * 64 * 8];
  gemm_body<false>(X, Wp, Y, xs, wsh, blockIdx.x * 64, threadIdx.x);
}

// ---------------- fused agg2 + per-graph readout (gid sorted) ----------------
__global__ __launch_bounds__(256) void k_agg_ro(const ushort* __restrict__ H,
                                                const ushort* __restrict__ csr16,
                                                const int* __restrict__ cnt,
                                                const int* __restrict__ gid,
                                                float* __restrict__ gsum,
                                                float* __restrict__ gcnt) {
  __shared__ float rows[8][128];
  __shared__ int gids[8];
  const int w = threadIdx.x >> 6;
  const int l = threadIdx.x & 63;
  const int h = l >> 5, q = l & 31;
  const int slot = w * 2 + h;
  const int node = blockIdx.x * 8 + slot;  // exact
  const int deg = min(cnt[node], SLOT);
  const ushort* nb = csr16 + (size_t)node * SLOT;
  const uint2* __restrict__ Hv = (const uint2*)H;
  float4 a = gather_sum(Hv, nb, deg, q);
  uint2 uh = Hv[(size_t)node * 32 + q];
  float inv = 1.0f / (float)(deg + 1);
  // x2 rounds through bf16 before the graph-mean (matches prior numerics)
  float4 rr;
  rr.x = bf2f_s(f2bf((bf2f_lo(uh.x) + a.x) * inv));
  rr.y = bf2f_s(f2bf((bf2f_hi(uh.x) + a.y) * inv));
  rr.z = bf2f_s(f2bf((bf2f_lo(uh.y) + a.z) * inv));
  rr.w = bf2f_s(f2bf((bf2f_hi(uh.y) + a.w) * inv));
  *(float4*)&rows[slot][q * 4] = rr;
  if (q == 0) gids[slot] = gid[node];
  __syncthreads();
  const int t = threadIdx.x;
  if (t < 128) {
    float acc = rows[0][t];
    int g = gids[0];
#pragma unroll
    for (int r = 1; r < 8; ++r) {
      int gr = gids[r];
      if (gr != g) {
        atomicAdd(&gsum[g * 128 + t], acc);
        acc = 0.f;
        g = gr;
      }
      acc += rows[r][t];
    }
    atomicAdd(&gsum[g * 128 + t], acc);
  } else if (t == 128) {
    float c = 1.f;
    int g = gids[0];
#pragma unroll
    for (int r = 1; r < 8; ++r) {
      int gr = gids[r];
      if (gr != g) {
        atomicAdd(&gcnt[g], c);
        c = 0.f;
        g = gr;
      }
      c += 1.f;
    }
    atomicAdd(&gcnt[g], c);
  }
}

// ---------------- gmean @ mlp_w + b, log_softmax ----------------
__global__ __launch_bounds__(128) void k_mlp(const float* __restrict__ gsum,
                                             const float* __restrict__ gcnt,
                                             const float* __restrict__ Wm,
                                             const float* __restrict__ bm,
                                             float* __restrict__ out) {
  __shared__ float m[128];
  __shared__ float lg[NCLASS];
  const int g = blockIdx.x;
  const int t = threadIdx.x;
  float cnt = fmaxf(gcnt[g], 1.0f);
  m[t] = gsum[g * 128 + t] / cnt;
  __syncthreads();
  if (t < NCLASS) {
    float s = bm[t];
#pragma unroll
    for (int k = 0; k < 128; ++k) s += m[k] * Wm[k * NCLASS + t];
    lg[t] = s;
  }
  __syncthreads();
  if (t < NCLASS) {
    float mx = lg[0];
#pragma unroll
    for (int i = 1; i < NCLASS; ++i) mx = fmaxf(mx, lg[i]);
    float sum = 0.f;
#pragma unroll
    for (int i = 0; i < NCLASS; ++i) sum += expf(lg[i] - mx);
    out[g * NCLASS + t] = lg[t] - mx - logf(sum);
  }
}

extern "C" void kernel_launch(void* const* d_in, const int* in_sizes, int n_in,
                              void* d_out, int out_size, void* d_ws, size_t ws_size,
                              hipStream_t stream) {
  const float* feat = (const float*)d_in[0];
  const float* W1   = (const float*)d_in[1];
  const float* W2   = (const float*)d_in[2];
  const float* Wm   = (const float*)d_in[3];
  const float* bm   = (const float*)d_in[4];
  const int* esrc   = (const int*)d_in[5];
  const int* edst   = (const int*)d_in[6];
  const int* gid    = (const int*)d_in[7];
  float* out = (float*)d_out;

  // workspace layout:
  // ints:   cnt[50048]
  // ushort: csr16[50000*64] | wp1[16384] | wp2[16384] | bufA[6.4M] | bufB[6.4M]
  // float:  gsum[512*128] | gcnt[512]
  int* cnt      = (int*)d_ws;
  ushort* csr16 = (ushort*)(cnt + 50048);
  ushort* wp1   = csr16 + (size_t)N_NODES * SLOT;
  ushort* wp2   = wp1 + 16384;
  ushort* bufA  = wp2 + 16384;
  ushort* bufB  = bufA + (size_t)N_NODES * NHID;
  float* gsum   = (float*)(bufB + (size_t)N_NODES * NHID);
  float* gcnt   = gsum + NUM_GRAPHS * NHID;

  hipMemsetAsync(cnt, 0, (size_t)50048 * sizeof(int), stream);
  hipMemsetAsync(gsum, 0, (size_t)(NUM_GRAPHS * NHID + 512) * sizeof(float), stream);

  // pack W1,W2 into MFMA B-fragment order (tiny)
  k_wpack<<<128, 256, 0, stream>>>(W1, W2, wp1, wp2);

  // fused: gemm1 (feat@W1 -> bufA bf16) + XCD-sliced slot-CSR bucket
  k_fused1<<<G1_GRID, 256, 0, stream>>>(feat, wp1, esrc, edst, cnt, csr16, bufA);

  // x1 = relu((h1+gather)/deg) -> bufB (bf16)
  k_agg1<<<N_NODES / 8, 256, 0, stream>>>(bufA, csr16, cnt, bufB);

  // h2 = x1@W2 -> bufA (bf16)
  k_gemm2<<<GEMM_BLOCKS, 256, 0, stream>>>(bufB, wp2, bufA);

  // x2 = (h2+gather)/deg fused with per-graph sum readout
  k_agg_ro<<<N_NODES / 8, 256, 0, stream>>>(bufA, csr16, cnt, gid, gsum, gcnt);

  k_mlp<<<NUM_GRAPHS, 128, 0, stream>>>(gsum, gcnt, Wm, bm, out);
}